// Round 5
// baseline (4975.493 us; speedup 1.0000x reference)
//
#include <hip/hip_runtime.h>
#include <hip/hip_bf16.h>

typedef unsigned short ushort_t;
typedef unsigned int   uint_t;

// Problem constants: T1=257, B=512, SD=128, AD=32, HS=512, SF=256, L=2
#define M_ALL 131584   // 257*512
#define M_SEQ 131072   // 256*512

// ---------- helpers ----------
__device__ __forceinline__ float bf2f(ushort_t u) {
    union { uint_t i; float f; } v; v.i = ((uint_t)u) << 16; return v.f;
}
__device__ __forceinline__ ushort_t f2bf(float f) {
    union { float f; uint_t i; } v; v.f = f;
    uint_t r = v.i + 0x7FFFu + ((v.i >> 16) & 1u);
    return (ushort_t)(r >> 16);
}
__device__ __forceinline__ ushort_t f2h(float f) {
    union { _Float16 h; ushort_t u; } v; v.h = (_Float16)f; return v.u;
}
__device__ __forceinline__ float fsigm(float x) { return 1.f / (1.f + __expf(-x)); }
__device__ __forceinline__ float ftanh(float x) {
    x = fminf(15.f, fmaxf(-15.f, x));
    float e = __expf(2.f * x);
    return (e - 1.f) / (e + 1.f);
}

typedef __attribute__((ext_vector_type(8))) short  bfrag;   // 8 x bf16
typedef __attribute__((ext_vector_type(4))) float  ffrag;   // 4 x f32 accum
typedef __attribute__((ext_vector_type(2))) _Float16 h2v;   // 2 x f16

__device__ __forceinline__ h2v as_h2(uint_t x) {
    union { uint_t u; h2v h; } v; v.u = x; return v.h;
}
// f16 pair dot with f32 accumulate: v_dot2_f32_f16 (proven R2-R4)
__device__ __forceinline__ float dot2f(h2v a, h2v b, float acc) {
#if __has_builtin(__builtin_amdgcn_fdot2)
    return __builtin_amdgcn_fdot2(a, b, acc, false);
#else
    return acc + (float)a.x * (float)b.x + (float)a.y * (float)b.y;
#endif
}

// async global->LDS, 16B per lane; dest base must be wave-uniform (lane*16 auto)
typedef const __attribute__((address_space(1))) unsigned int as1_u32;
typedef __attribute__((address_space(3))) unsigned int as3_u32;
__device__ __forceinline__ void gload16(const void* g, void* l) {
    __builtin_amdgcn_global_load_lds((as1_u32*)g, (as3_u32*)l, 16, 0, 0);
}

// manual stage of 8 elements into LDS as bf16 (f32 source converts)
__device__ __forceinline__ void stage8(const float* p, ushort_t* dst) {
    const float4 a = *(const float4*)p;
    const float4 b = *(const float4*)(p + 4);
    bfrag v;
    v[0] = (short)f2bf(a.x); v[1] = (short)f2bf(a.y);
    v[2] = (short)f2bf(a.z); v[3] = (short)f2bf(a.w);
    v[4] = (short)f2bf(b.x); v[5] = (short)f2bf(b.y);
    v[6] = (short)f2bf(b.z); v[7] = (short)f2bf(b.w);
    *(bfrag*)dst = v;
}

// ---------- 128x128-tile bf16 MFMA GEMM, counted-vmcnt 2-phase pipeline ----------
// C = act(A @ W^T + bias), C bf16, W bf16, bias f32.
// T4 counted wait: per K-iter {stage(next); vmcnt(N)=just-issued count -> previous
// tile's loads drained, THIS iter's stay in flight across both barriers; barrier;
// compute(cur); lgkmcnt(0)+barrier (ds_reads drained before buffer reuse)}.
// Mixed f32-staging paths (stage8 -> ds_write) use vmcnt(2)+lgkmcnt(0).
// AMODE 0: plain A1 (stride K)
// AMODE 1: k<256 -> A1 stride 256 ; k>=256 -> A2 stride 32  (x = [sf, action]), A2 f32
// AMODE 2: k<256 -> A1 stride 256 ; k>=256 -> A2 stride 256 (xi = [sf, pred_next])
template<int AMODE, int ACT, typename TA1, typename TA2>
__global__ __launch_bounds__(256) void gemm_k(
    const TA1* __restrict__ A1, const TA2* __restrict__ A2,
    const ushort_t* __restrict__ W, const float* __restrict__ b1,
    ushort_t* __restrict__ C, int K, int N)
{
    __shared__ __align__(16) ushort_t As[2][128][32];
    __shared__ __align__(16) ushort_t Ws[2][128][32];

    const int tid  = threadIdx.x;
    const int m0   = blockIdx.x * 128;
    const int n0   = blockIdx.y * 128;
    const int lane = tid & 63;
    const int wv   = tid >> 6;
    const int wm   = (wv & 1) * 64;
    const int wn   = (wv >> 1) * 64;
    const int quad = lane >> 4;
    const int ln   = lane & 15;

    ffrag acc[4][4];
#pragma unroll
    for (int i = 0; i < 4; i++)
#pragma unroll
        for (int j = 0; j < 4; j++) acc[i][j] = (ffrag){0.f, 0.f, 0.f, 0.f};

    const int grow = lane >> 2;        // row within a 16-row gload group
    const int gcol = (lane & 3) * 8;   // element col 0,8,16,24
    const int arow = tid >> 2;         // manual-stage row (0..63; +64 via rr)
    const int acol = (tid & 3) * 8;

    auto stage = [&](int buf, int k0) {
#pragma unroll
        for (int c = 0; c < 2; c++) {
            const int rb = (wv << 5) + (c << 4);
            gload16(W + (size_t)(n0 + rb + grow) * K + k0 + gcol, &Ws[buf][rb][0]);
        }
        if constexpr (sizeof(TA1) == 4) {
#pragma unroll
            for (int rr = 0; rr < 2; rr++)
                stage8((const float*)A1 + (size_t)(m0 + arow + rr * 64) * K + k0 + acol,
                       &As[buf][arow + rr * 64][acol]);
        } else {
            if (AMODE == 1 && sizeof(TA2) == 4 && k0 >= 256) {
#pragma unroll
                for (int rr = 0; rr < 2; rr++)
                    stage8((const float*)A2 + (size_t)(m0 + arow + rr * 64) * 32 + (k0 - 256) + acol,
                           &As[buf][arow + rr * 64][acol]);
            } else {
#pragma unroll
                for (int c = 0; c < 2; c++) {
                    const int rb = (wv << 5) + (c << 4);
                    const int r  = rb + grow;
                    const ushort_t* src;
                    if (AMODE == 0)     src = (const ushort_t*)A1 + (size_t)(m0 + r) * K + k0 + gcol;
                    else if (k0 < 256)  src = (const ushort_t*)A1 + (size_t)(m0 + r) * 256 + k0 + gcol;
                    else                src = (const ushort_t*)A2 + (size_t)(m0 + r) * 256 + (k0 - 256) + gcol; // AMODE 2
                    gload16(src, &As[buf][rb][0]);
                }
            }
        }
    };
    auto compute = [&](int buf) {
        bfrag af[4], bfv[4];
#pragma unroll
        for (int i = 0; i < 4; i++) af[i]  = *(const bfrag*)&As[buf][wm + i * 16 + ln][quad * 8];
#pragma unroll
        for (int j = 0; j < 4; j++) bfv[j] = *(const bfrag*)&Ws[buf][wn + j * 16 + ln][quad * 8];
#pragma unroll
        for (int i = 0; i < 4; i++)
#pragma unroll
            for (int j = 0; j < 4; j++)
                acc[i][j] = __builtin_amdgcn_mfma_f32_16x16x32_bf16(af[i], bfv[j], acc[i][j], 0, 0, 0);
    };

    stage(0, 0);
    int cur = 0;
    for (int k0 = 32; k0 < K; k0 += 32) {
        stage(cur ^ 1, k0);   // issue next tile; stays in flight through compute
        // counted wait: drain PREVIOUS tile's staging only
        if constexpr (sizeof(TA1) == 4) {
            asm volatile("s_waitcnt vmcnt(2) lgkmcnt(0)" ::: "memory");
        } else if constexpr (AMODE == 1 && sizeof(TA2) == 4) {
            if (k0 >= 256) asm volatile("s_waitcnt vmcnt(2) lgkmcnt(0)" ::: "memory");
            else           asm volatile("s_waitcnt vmcnt(4)" ::: "memory");
        } else {
            asm volatile("s_waitcnt vmcnt(4)" ::: "memory");
        }
        __builtin_amdgcn_sched_barrier(0);
        asm volatile("s_barrier" ::: "memory");
        compute(cur);
        // drain own ds_reads before partner waves may overwrite this buffer
        asm volatile("s_waitcnt lgkmcnt(0)" ::: "memory");
        __builtin_amdgcn_sched_barrier(0);
        asm volatile("s_barrier" ::: "memory");
        cur ^= 1;
    }
    asm volatile("s_waitcnt vmcnt(0) lgkmcnt(0)" ::: "memory");
    __builtin_amdgcn_sched_barrier(0);
    asm volatile("s_barrier" ::: "memory");
    compute(cur);

#pragma unroll
    for (int j = 0; j < 4; j++) {
        const int n = n0 + wn + j * 16 + ln;
        const float bias = b1[n];
#pragma unroll
        for (int i = 0; i < 4; i++) {
#pragma unroll
            for (int r = 0; r < 4; r++) {
                const int m = m0 + wm + i * 16 + quad * 4 + r;
                float x = acc[i][j][r] + bias;
                if (ACT == 1) x = fmaxf(x, 0.f);
                C[(size_t)m * N + n] = f2bf(x);
            }
        }
    }
}

// ---------- prep ----------
// wt0/wt1: f16 pair-pack [k2][u][8] f16:
//   8 = {wi(2k2),wi(2k2+1), wf(2k2),wf(2k2+1), wg(2k2),wg(2k2+1), wo(2k2),wo(2k2+1)}
// -> uint4 per (k2,u) = 4 gate k-pairs, feeds v_dot2_f32_f16 directly.
struct PrepArgs {
    const float *Wfe, *Wih0, *Whh0, *bih0, *bhh0, *Wih1, *Whh1, *bih1, *bhh1;
    const float *Wf1, *Wf2, *Wm1, *Ws1, *Wm2, *Ws2;
    const float *bm1, *bs1;
    ushort_t *Wfe_b, *Wih0_b, *Wih1_b, *wt0, *wt1, *Wf1_b, *Wf2_b, *Wms_b;
    float *W2t, *bias0s, *bias1s, *bms;
};
__global__ __launch_bounds__(256) void prep_k(PrepArgs a)
{
    const int idx = blockIdx.x * 256 + threadIdx.x;
    const int stride = gridDim.x * 256;
    for (int e = idx; e < 65536; e += stride)  a.Wfe_b[e]  = f2bf(a.Wfe[e]);
    for (int e = idx; e < 524288; e += stride) a.Wih0_b[e] = f2bf(a.Wih0[e]);   // (1024,512)
    for (int e = idx; e < 262144; e += stride) a.Wih1_b[e] = f2bf(a.Wih1[e]);   // (1024,256)
    for (int e = idx; e < 262144; e += stride) {              // wt0: f16 pair-pack (Whh0)
        const int k2 = e >> 11, r = e & 2047;
        const int u = r >> 3, t = r & 7;
        const int g = t >> 1, wh = t & 1;
        const int kk = (k2 << 1) + wh;
        a.wt0[e] = f2h(a.Whh0[(g * 256 + u) * 256 + kk]);
    }
    for (int e = idx; e < 262144; e += stride) {              // wt1: f16 pair-pack (Whh1)
        const int k2 = e >> 11, r = e & 2047;
        const int u = r >> 3, t = r & 7;
        const int g = t >> 1, wh = t & 1;
        const int kk = (k2 << 1) + wh;
        a.wt1[e] = f2h(a.Whh1[(g * 256 + u) * 256 + kk]);
    }
    for (int e = idx; e < 147456; e += stride) a.Wf1_b[e] = f2bf(a.Wf1[e]);
    for (int e = idx; e < 131072; e += stride) a.Wf2_b[e] = f2bf(a.Wf2[e]);
    for (int e = idx; e < 524288; e += stride) {              // Wms_b: (1024,512) = [Wm1; Ws1]
        const int n = e >> 9, k = e & 511;
        a.Wms_b[e] = f2bf((n < 512) ? a.Wm1[n * 512 + k] : a.Ws1[(n - 512) * 512 + k]);
    }
    for (int e = idx; e < 32768; e += stride) {               // W2t: (512,64) k-major f32
        const int k = e >> 6, c = e & 63;
        a.W2t[e] = (c < 32) ? a.Wm2[c * 512 + k] : a.Ws2[(c - 32) * 512 + k];
    }
    for (int e = idx; e < 1024; e += stride) {
        a.bias0s[e] = a.bih0[e] + a.bhh0[e];
        a.bias1s[e] = a.bih1[e] + a.bhh1[e];
        a.bms[e]    = (e < 512) ? a.bm1[e] : a.bs1[e - 512];
    }
}

// ---------- persistent-register LSTM scan (1 barrier/step) ----------
// 256 blocks x 512 threads; block owns 2 batch rows. Thread (r=tid&1, u=tid>>1)
// holds the weight quads for unit u over k2 in [r*64, r*64+64) in 256 VGPRs.
// Partner thread = tid^1 (SAME wave) -> partial exchange via __shfl_xor, no LDS,
// no second barrier. xs double-buffered by phase -> single barrier per step.
// xg gate loads + next-step done mask issued BEFORE the barrier/dot-loop so
// their L3 latency hides under ~2000 cyc of v_dot2 (R4: loads were issued
// after the dot loop -> full latency exposed -> VALUBusy 38%).
struct ScanArgs {
    const ushort_t* xg;      // (nsteps*512, 1024) bf16, gate order {i,f,g,o}x256
    const int*      dones;   // (257,512) int32, absolute t indexing
    const ushort_t* wt;      // f16 pair-packed recurrent weights [k2][u][8]
    ushort_t*       hout;    // bf16 h stream: (nsteps*512, 256), chunk-local s indexing
    float*          hst;     // persistent h (512*256 f32)
    float*          cst;     // persistent c (512*256 f32)
    int jc, nsteps, init;
};

#define DOTQ(W, H0, H1) do { \
    const h2v q0 = as_h2(H0), q1 = as_h2(H1); \
    p0i = dot2f(q0, as_h2((W).x), p0i); p0f = dot2f(q0, as_h2((W).y), p0f); \
    p0g = dot2f(q0, as_h2((W).z), p0g); p0o = dot2f(q0, as_h2((W).w), p0o); \
    p1i = dot2f(q1, as_h2((W).x), p1i); p1f = dot2f(q1, as_h2((W).y), p1f); \
    p1g = dot2f(q1, as_h2((W).z), p1g); p1o = dot2f(q1, as_h2((W).w), p1o); \
} while (0)

__global__ __launch_bounds__(512, 1) void scan_r_k(ScanArgs a)
{
    __shared__ __align__(16) _Float16 xs[2][2][256];   // [phase][row][unit]
    const int tid = threadIdx.x;
    const int r = tid & 1, u = tid >> 1;
    const int b = blockIdx.x * 2 + r;
    float h = a.init ? 0.f : a.hst[b * 256 + u];
    float c = a.init ? 0.f : a.cst[b * 256 + u];

    // preload 64 weight quads (k2 = r*64 + j) into registers
    uint4 wr[64];
    {
        const ushort_t* wtu = a.wt + ((size_t)(r * 64) << 11) + 8 * u;
#pragma unroll
        for (int j = 0; j < 64; ++j)
            wr[j] = *(const uint4*)(wtu + ((size_t)j << 11));
    }
    const int ks = r * 128;   // h-index base of this thread's k-half
    int ph = 0;
    float mval = 1.f - (float)a.dones[(size_t)a.jc * 512 + b];

    for (int sst = 0; sst < a.nsteps; ++sst) {
        xs[ph][r][u] = (_Float16)(h * mval);
        const float cold = c * mval;
        // prefetch next step's done mask (consumed next iteration)
        float mnext = 0.f;
        if (sst + 1 < a.nsteps)
            mnext = 1.f - (float)a.dones[(size_t)(a.jc + sst + 1) * 512 + b];
        // issue xg gate loads now; consumed after the dot loop
        const size_t base = ((size_t)sst * 512 + b) * 1024;
        const ushort_t g0 = a.xg[base + u];
        const ushort_t g1 = a.xg[base + 256 + u];
        const ushort_t g2 = a.xg[base + 512 + u];
        const ushort_t g3 = a.xg[base + 768 + u];
        __syncthreads();

        float p0i = 0.f, p0f = 0.f, p0g = 0.f, p0o = 0.f;   // row 0 partial (this k-half)
        float p1i = 0.f, p1f = 0.f, p1g = 0.f, p1o = 0.f;   // row 1 partial (this k-half)
#pragma unroll
        for (int jj = 0; jj < 16; ++jj) {
            const uint4 h0 = *(const uint4*)&xs[ph][0][ks + jj * 8];
            const uint4 h1 = *(const uint4*)&xs[ph][1][ks + jj * 8];
            DOTQ(wr[jj * 4 + 0], h0.x, h1.x);
            DOTQ(wr[jj * 4 + 1], h0.y, h1.y);
            DOTQ(wr[jj * 4 + 2], h0.z, h1.z);
            DOTQ(wr[jj * 4 + 3], h0.w, h1.w);
        }

        // exchange other-half partials with partner lane (tid^1, same wave)
        const float s0 = (r == 0) ? p1i : p0i;
        const float s1 = (r == 0) ? p1f : p0f;
        const float s2 = (r == 0) ? p1g : p0g;
        const float s3 = (r == 0) ? p1o : p0o;
        const float o0 = __shfl_xor(s0, 1);
        const float o1 = __shfl_xor(s1, 1);
        const float o2 = __shfl_xor(s2, 1);
        const float o3 = __shfl_xor(s3, 1);

        const float ai  = ((r == 0) ? p0i : p1i) + o0 + bf2f(g0);
        const float af2 = ((r == 0) ? p0f : p1f) + o1 + bf2f(g1);
        const float ag  = ((r == 0) ? p0g : p1g) + o2 + bf2f(g2);
        const float ao  = ((r == 0) ? p0o : p1o) + o3 + bf2f(g3);

        const float c2 = fsigm(af2) * cold + fsigm(ai) * ftanh(ag);
        const float h2 = fsigm(ao) * ftanh(c2);
        c = c2; h = h2;
        a.hout[((size_t)sst * 512 + b) * 256 + u] = f2bf(h2);
        mval = mnext;
        ph ^= 1;
    }
    a.hst[b * 256 + u] = h;
    a.cst[b * 256 + u] = c;
}

// ---------- forward loss + intrinsic reward (row-chunked), f32 out ----------
__global__ __launch_bounds__(256) void fl_k(const ushort_t* __restrict__ pn,
                                            const ushort_t* __restrict__ outs,
                                            float* __restrict__ out, float* __restrict__ acc,
                                            int r0, int out_size)
{
    __shared__ float bs[4];
    const int tid = threadIdx.x;
    const int w = tid >> 6, l = tid & 63;
    const size_t rl = (size_t)blockIdx.x * 4 + w;
    const size_t rg = rl + r0;
    const ushort_t* p = pn + rl * 256;
    const ushort_t* q = outs + (rg + 512) * 256;   // next_state_features = outs[t+1]
    float s = 0.f;
#pragma unroll
    for (int i = 0; i < 4; i++) {
        const float d = bf2f(p[l + i * 64]) - bf2f(q[l + i * 64]);
        s += d * d;
    }
#pragma unroll
    for (int off = 32; off > 0; off >>= 1) s += __shfl_down(s, off);
    if (l == 0) { if ((long long)(2 + rg) < out_size) out[2 + rg] = s; bs[w] = s; }
    __syncthreads();
    if (tid == 0) atomicAdd(acc, bs[0] + bs[1] + bs[2] + bs[3]);
}

// ---------- fused mu/std heads + inverse loss (row-chunked), packed msh ----------
__global__ __launch_bounds__(256) void musd_k(
    const ushort_t* __restrict__ msh,    // (rows, 1024): [mh | sh]
    const float* __restrict__ W2t, const float* __restrict__ bm2,
    const float* __restrict__ bs2, const float* __restrict__ action,
    float* __restrict__ acc, int r0)
{
    __shared__ __align__(16) ushort_t mhs[8][512];
    __shared__ __align__(16) ushort_t shs[8][512];
    __shared__ float red[256];
    const int tid = threadIdx.x;
    const size_t rl0 = (size_t)blockIdx.x * 8;
    for (int i = tid; i < 512; i += 256) {
        const int row = i >> 6, c = (i & 63) * 8;
        *(uint4*)&mhs[row][c] = *(const uint4*)&msh[(rl0 + row) * 1024 + c];
        *(uint4*)&shs[row][c] = *(const uint4*)&msh[(rl0 + row) * 1024 + 512 + c];
    }
    __syncthreads();
    const int row = tid >> 5, c = tid & 31;
    float am = bm2[c], asv = bs2[c];
    for (int k = 0; k < 512; k += 8) {
#pragma unroll
        for (int e = 0; e < 8; e++) {
            const float wm = W2t[(k + e) * 64 + c];
            const float wsv = W2t[(k + e) * 64 + 32 + c];
            am  += bf2f(mhs[row][k + e]) * wm;
            asv += bf2f(shs[row][k + e]) * wsv;
        }
    }
    const float mu = ftanh(am);
    const float sp = fmaxf(asv, 0.f) + log1pf(__expf(-fabsf(asv)));   // softplus
    const float a  = action[(rl0 + r0 + row) * 32 + c];
    const float z  = (a - mu) / sp;
    red[tid] = 0.5f * z * z + __logf(sp) + 0.918938533204672741f;     // -log_prob
    __syncthreads();
    for (int s = 128; s > 0; s >>= 1) { if (tid < s) red[tid] += red[tid + s]; __syncthreads(); }
    if (tid == 0) atomicAdd(acc, red[0]);
}

// ---------- finalize: scalar losses + hidden copy-out (f32) ----------
__global__ __launch_bounds__(256) void fin_k(const float* __restrict__ acc,
                                             const float* __restrict__ h0st,
                                             const float* __restrict__ h1st,
                                             const float* __restrict__ c0st,
                                             const float* __restrict__ c1st,
                                             float* __restrict__ out, int out_size)
{
    const size_t idx = (size_t)blockIdx.x * 256 + threadIdx.x;
    if (idx == 0 && out_size > 0) out[0] = acc[0] / 33554432.f;   // mean over 256*512*256
    if (idx == 1 && out_size > 1) out[1] = acc[1] / 4194304.f;    // mean over 256*512*32
    if (idx < 524288) {
        const int which = (int)(idx >> 17);
        const int local = (int)(idx & 131071);
        float v;
        if      (which == 0) v = h0st[local];
        else if (which == 1) v = h1st[local];
        else if (which == 2) v = c0st[local];
        else                 v = c1st[local];
        const size_t o = 2 + 131072 + idx;
        if ((long long)o < out_size) out[o] = v;
    }
}

extern "C" void kernel_launch(void* const* d_in, const int* in_sizes, int n_in,
                              void* d_out, int out_size, void* d_ws, size_t ws_size,
                              hipStream_t stream)
{
    const float* states = (const float*)d_in[0];
    const float* action = (const float*)d_in[1];
    const int*   dones  = (const int*)d_in[2];
    const float* Wfe  = (const float*)d_in[3];
    const float* bfe  = (const float*)d_in[4];
    const float* Wih0 = (const float*)d_in[5];
    const float* Whh0 = (const float*)d_in[6];
    const float* bih0 = (const float*)d_in[7];
    const float* bhh0 = (const float*)d_in[8];
    const float* Wih1 = (const float*)d_in[9];
    const float* Whh1 = (const float*)d_in[10];
    const float* bih1 = (const float*)d_in[11];
    const float* bhh1 = (const float*)d_in[12];
    const float* Wf1  = (const float*)d_in[13];
    const float* bf1  = (const float*)d_in[14];
    const float* Wf2  = (const float*)d_in[15];
    const float* bf2  = (const float*)d_in[16];
    const float* Wm1  = (const float*)d_in[17];
    const float* bm1  = (const float*)d_in[18];
    const float* Wm2  = (const float*)d_in[19];
    const float* bm2  = (const float*)d_in[20];
    const float* Ws1  = (const float*)d_in[21];
    const float* bs1  = (const float*)d_in[22];
    const float* Ws2  = (const float*)d_in[23];
    const float* bs2  = (const float*)d_in[24];

    // ---------- workspace layout (persistent region) ----------
    char* ws = (char*)d_ws;
    size_t off = 0;
    ushort_t* outs    = (ushort_t*)(ws + off); off += 67371008;  // 257*512*256 bf16
    float*    h0st    = (float*)(ws + off);    off += 524288;
    float*    c0st    = (float*)(ws + off);    off += 524288;
    float*    h1st    = (float*)(ws + off);    off += 524288;
    float*    c1st    = (float*)(ws + off);    off += 524288;
    ushort_t* wt0     = (ushort_t*)(ws + off); off += 524288;    // f16 pairs [k2][u][8]
    ushort_t* wt1     = (ushort_t*)(ws + off); off += 524288;    // f16 pairs [k2][u][8]
    ushort_t* Wfe_b   = (ushort_t*)(ws + off); off += 131072;
    ushort_t* Wih0_b  = (ushort_t*)(ws + off); off += 1048576;
    ushort_t* Wih1_b  = (ushort_t*)(ws + off); off += 524288;
    ushort_t* Wf1_b   = (ushort_t*)(ws + off); off += 294912;
    ushort_t* Wf2_b   = (ushort_t*)(ws + off); off += 262144;
    ushort_t* Wms_b   = (ushort_t*)(ws + off); off += 1048576;
    float*    W2t     = (float*)(ws + off);    off += 131072;
    float*    bias0s  = (float*)(ws + off);    off += 4096;
    float*    bias1s  = (float*)(ws + off);    off += 4096;
    float*    bms     = (float*)(ws + off);    off += 4096;
    float*    accp    = (float*)(ws + off);    off += 256;
    char*     S       = ws + off;              // chunk scratch
    const size_t avail = (ws_size > off) ? (ws_size - off) : 0;

    // scan-phase chunk with buffer overlay:
    //   xgck: TC x 1 MB   (xg0, then xg1 reuses it — xg0 dead after scan0)
    //   fck : TC x 512 KB (feats, then h0s overlays — feats dead after xg0 GEMM)
    const size_t STEP_B = 1572864;
    int TC = (int)(avail / STEP_B);
    if (TC > 257) TC = 257;
    if (TC < 1)  TC = 1;
    // head-phase chunk: per row ph(1024)+pn(512)+msh(2048) = 3584 B; cap 24576 rows (~88 MB)
    long long rc = (long long)(avail / 3584) & ~127LL;
    if (rc > 24576) rc = 24576;
    if (rc < 128)   rc = 128;
    const int RC = (int)rc;

    hipMemsetAsync(accp, 0, 256, stream);

    PrepArgs pa{ Wfe, Wih0, Whh0, bih0, bhh0, Wih1, Whh1, bih1, bhh1,
                 Wf1, Wf2, Wm1, Ws1, Wm2, Ws2, bm1, bs1,
                 Wfe_b, Wih0_b, Wih1_b, wt0, wt1, Wf1_b, Wf2_b, Wms_b,
                 W2t, bias0s, bias1s, bms };
    prep_k<<<512, 256, 0, stream>>>(pa);

    // ---------- scan phase ----------
    ushort_t* xgck = (ushort_t*)S;
    ushort_t* fck  = (ushort_t*)(S + (size_t)TC * 1048576);
    for (int jc = 0; jc < 257; jc += TC) {
        const int nsteps = (257 - jc < TC) ? (257 - jc) : TC;
        // feats = relu(states_chunk @ Wfe^T + bfe)      [N=512, K=128]
        gemm_k<0, 1, float, float><<<dim3(nsteps * 4, 4), 256, 0, stream>>>(
            states + (size_t)jc * 512 * 128, nullptr, Wfe_b, bfe, fck, 128, 512);
        // xg0 = feats @ Wih0^T + (bih0 + bhh0)          [N=1024, K=512]
        gemm_k<0, 0, ushort_t, ushort_t><<<dim3(nsteps * 4, 8), 256, 0, stream>>>(
            fck, nullptr, Wih0_b, bias0s, xgck, 512, 1024);
        // layer-0 scan — h0s overlays feats region
        ScanArgs sa0{ xgck, dones, wt0, fck, h0st, c0st, jc, nsteps, (jc == 0) ? 1 : 0 };
        scan_r_k<<<256, 512, 0, stream>>>(sa0);
        // xg1 = h0s @ Wih1^T + (bih1 + bhh1)            [N=1024, K=256] — xg1 reuses xgck
        gemm_k<0, 0, ushort_t, ushort_t><<<dim3(nsteps * 4, 8), 256, 0, stream>>>(
            fck, nullptr, Wih1_b, bias1s, xgck, 256, 1024);
        // layer-1 scan
        ScanArgs sa1{ xgck, dones, wt1, outs + (size_t)jc * 131072,
                      h1st, c1st, jc, nsteps, (jc == 0) ? 1 : 0 };
        scan_r_k<<<256, 512, 0, stream>>>(sa1);
    }

    // ---------- head phase (row-chunked, L3-resident chunks) ----------
    for (int r0 = 0; r0 < M_SEQ; r0 += RC) {
        const int rows = (M_SEQ - r0 < RC) ? (M_SEQ - r0) : RC;
        ushort_t* ph  = (ushort_t*)S;
        ushort_t* pn  = (ushort_t*)(S + (size_t)rows * 1024);
        ushort_t* msh = (ushort_t*)(S + (size_t)rows * 1536);
        // pred_hidden = relu([sf, action] @ Wf1^T + bf1)  [N=512, K=288]
        gemm_k<1, 1, ushort_t, float><<<dim3(rows / 128, 4), 256, 0, stream>>>(
            outs + (size_t)r0 * 256, action + (size_t)r0 * 32, Wf1_b, bf1, ph, 288, 512);
        // pred_next = pred_hidden @ Wf2^T + bf2           [N=256, K=512]
        gemm_k<0, 0, ushort_t, ushort_t><<<dim3(rows / 128, 2), 256, 0, stream>>>(
            ph, nullptr, Wf2_b, bf2, pn, 512, 256);
        // forward loss + intrinsic reward
        fl_k<<<rows / 4, 256, 0, stream>>>(pn, outs, (float*)d_out, accp, r0, out_size);
        // msh = relu([sf, pred_next] @ [Wm1;Ws1]^T + [bm1;bs1])  [N=1024, K=512]
        gemm_k<2, 1, ushort_t, ushort_t><<<dim3(rows / 128, 8), 256, 0, stream>>>(
            outs + (size_t)r0 * 256, pn, Wms_b, bms, msh, 512, 1024);
        // mu/std heads + inverse loss
        musd_k<<<rows / 8, 256, 0, stream>>>(msh, W2t, bm2, bs2, action, accp + 1, r0);
    }

    // scalars + hidden
    fin_k<<<2048, 256, 0, stream>>>(accp, h0st, h1st, c0st, c1st, (float*)d_out, out_size);
}

// Round 6
// 3466.903 us; speedup vs baseline: 1.4351x; 1.4351x over previous
//
#include <hip/hip_runtime.h>
#include <hip/hip_bf16.h>

typedef unsigned short ushort_t;
typedef unsigned int   uint_t;

// Problem constants: T1=257, B=512, SD=128, AD=32, HS=512, SF=256, L=2
#define M_ALL 131584   // 257*512
#define M_SEQ 131072   // 256*512

// ---------- helpers ----------
__device__ __forceinline__ float bf2f(ushort_t u) {
    union { uint_t i; float f; } v; v.i = ((uint_t)u) << 16; return v.f;
}
__device__ __forceinline__ ushort_t f2bf(float f) {
    union { float f; uint_t i; } v; v.f = f;
    uint_t r = v.i + 0x7FFFu + ((v.i >> 16) & 1u);
    return (ushort_t)(r >> 16);
}
__device__ __forceinline__ ushort_t f2h(float f) {
    union { _Float16 h; ushort_t u; } v; v.h = (_Float16)f; return v.u;
}
__device__ __forceinline__ float fsigm(float x) { return 1.f / (1.f + __expf(-x)); }
__device__ __forceinline__ float ftanh(float x) {
    x = fminf(15.f, fmaxf(-15.f, x));
    float e = __expf(2.f * x);
    return (e - 1.f) / (e + 1.f);
}

typedef __attribute__((ext_vector_type(8))) short  bfrag;   // 8 x bf16
typedef __attribute__((ext_vector_type(4))) float  ffrag;   // 4 x f32 accum
typedef __attribute__((ext_vector_type(2))) _Float16 h2v;   // 2 x f16

__device__ __forceinline__ h2v as_h2(uint_t x) {
    union { uint_t u; h2v h; } v; v.u = x; return v.h;
}
// f16 pair dot with f32 accumulate: v_dot2_f32_f16 (proven R2-R5)
__device__ __forceinline__ float dot2f(h2v a, h2v b, float acc) {
#if __has_builtin(__builtin_amdgcn_fdot2)
    return __builtin_amdgcn_fdot2(a, b, acc, false);
#else
    return acc + (float)a.x * (float)b.x + (float)a.y * (float)b.y;
#endif
}

// async global->LDS, 16B per lane; dest base must be wave-uniform (lane*16 auto)
typedef const __attribute__((address_space(1))) unsigned int as1_u32;
typedef __attribute__((address_space(3))) unsigned int as3_u32;
__device__ __forceinline__ void gload16(const void* g, void* l) {
    __builtin_amdgcn_global_load_lds((as1_u32*)g, (as3_u32*)l, 16, 0, 0);
}

// manual stage of 8 elements into LDS as bf16 (f32 source converts)
__device__ __forceinline__ void stage8(const float* p, ushort_t* dst) {
    const float4 a = *(const float4*)p;
    const float4 b = *(const float4*)(p + 4);
    bfrag v;
    v[0] = (short)f2bf(a.x); v[1] = (short)f2bf(a.y);
    v[2] = (short)f2bf(a.z); v[3] = (short)f2bf(a.w);
    v[4] = (short)f2bf(b.x); v[5] = (short)f2bf(b.y);
    v[6] = (short)f2bf(b.z); v[7] = (short)f2bf(b.w);
    *(bfrag*)dst = v;
}

// ---------- 128x128-tile bf16 MFMA GEMM, counted-vmcnt 2-phase pipeline ----------
// C = act(A @ W^T + bias), C bf16, W bf16, bias f32.  (unchanged from R5)
// AMODE 0: plain A1 (stride K)
// AMODE 1: k<256 -> A1 stride 256 ; k>=256 -> A2 stride 32  (x = [sf, action]), A2 f32
// AMODE 2: k<256 -> A1 stride 256 ; k>=256 -> A2 stride 256 (xi = [sf, pred_next])
template<int AMODE, int ACT, typename TA1, typename TA2>
__global__ __launch_bounds__(256) void gemm_k(
    const TA1* __restrict__ A1, const TA2* __restrict__ A2,
    const ushort_t* __restrict__ W, const float* __restrict__ b1,
    ushort_t* __restrict__ C, int K, int N)
{
    __shared__ __align__(16) ushort_t As[2][128][32];
    __shared__ __align__(16) ushort_t Ws[2][128][32];

    const int tid  = threadIdx.x;
    const int m0   = blockIdx.x * 128;
    const int n0   = blockIdx.y * 128;
    const int lane = tid & 63;
    const int wv   = tid >> 6;
    const int wm   = (wv & 1) * 64;
    const int wn   = (wv >> 1) * 64;
    const int quad = lane >> 4;
    const int ln   = lane & 15;

    ffrag acc[4][4];
#pragma unroll
    for (int i = 0; i < 4; i++)
#pragma unroll
        for (int j = 0; j < 4; j++) acc[i][j] = (ffrag){0.f, 0.f, 0.f, 0.f};

    const int grow = lane >> 2;        // row within a 16-row gload group
    const int gcol = (lane & 3) * 8;   // element col 0,8,16,24
    const int arow = tid >> 2;         // manual-stage row (0..63; +64 via rr)
    const int acol = (tid & 3) * 8;

    auto stage = [&](int buf, int k0) {
#pragma unroll
        for (int c = 0; c < 2; c++) {
            const int rb = (wv << 5) + (c << 4);
            gload16(W + (size_t)(n0 + rb + grow) * K + k0 + gcol, &Ws[buf][rb][0]);
        }
        if constexpr (sizeof(TA1) == 4) {
#pragma unroll
            for (int rr = 0; rr < 2; rr++)
                stage8((const float*)A1 + (size_t)(m0 + arow + rr * 64) * K + k0 + acol,
                       &As[buf][arow + rr * 64][acol]);
        } else {
            if (AMODE == 1 && sizeof(TA2) == 4 && k0 >= 256) {
#pragma unroll
                for (int rr = 0; rr < 2; rr++)
                    stage8((const float*)A2 + (size_t)(m0 + arow + rr * 64) * 32 + (k0 - 256) + acol,
                           &As[buf][arow + rr * 64][acol]);
            } else {
#pragma unroll
                for (int c = 0; c < 2; c++) {
                    const int rb = (wv << 5) + (c << 4);
                    const int r  = rb + grow;
                    const ushort_t* src;
                    if (AMODE == 0)     src = (const ushort_t*)A1 + (size_t)(m0 + r) * K + k0 + gcol;
                    else if (k0 < 256)  src = (const ushort_t*)A1 + (size_t)(m0 + r) * 256 + k0 + gcol;
                    else                src = (const ushort_t*)A2 + (size_t)(m0 + r) * 256 + (k0 - 256) + gcol; // AMODE 2
                    gload16(src, &As[buf][rb][0]);
                }
            }
        }
    };
    auto compute = [&](int buf) {
        bfrag af[4], bfv[4];
#pragma unroll
        for (int i = 0; i < 4; i++) af[i]  = *(const bfrag*)&As[buf][wm + i * 16 + ln][quad * 8];
#pragma unroll
        for (int j = 0; j < 4; j++) bfv[j] = *(const bfrag*)&Ws[buf][wn + j * 16 + ln][quad * 8];
#pragma unroll
        for (int i = 0; i < 4; i++)
#pragma unroll
            for (int j = 0; j < 4; j++)
                acc[i][j] = __builtin_amdgcn_mfma_f32_16x16x32_bf16(af[i], bfv[j], acc[i][j], 0, 0, 0);
    };

    stage(0, 0);
    int cur = 0;
    for (int k0 = 32; k0 < K; k0 += 32) {
        stage(cur ^ 1, k0);   // issue next tile; stays in flight through compute
        if constexpr (sizeof(TA1) == 4) {
            asm volatile("s_waitcnt vmcnt(2) lgkmcnt(0)" ::: "memory");
        } else if constexpr (AMODE == 1 && sizeof(TA2) == 4) {
            if (k0 >= 256) asm volatile("s_waitcnt vmcnt(2) lgkmcnt(0)" ::: "memory");
            else           asm volatile("s_waitcnt vmcnt(4)" ::: "memory");
        } else {
            asm volatile("s_waitcnt vmcnt(4)" ::: "memory");
        }
        __builtin_amdgcn_sched_barrier(0);
        asm volatile("s_barrier" ::: "memory");
        compute(cur);
        asm volatile("s_waitcnt lgkmcnt(0)" ::: "memory");
        __builtin_amdgcn_sched_barrier(0);
        asm volatile("s_barrier" ::: "memory");
        cur ^= 1;
    }
    asm volatile("s_waitcnt vmcnt(0) lgkmcnt(0)" ::: "memory");
    __builtin_amdgcn_sched_barrier(0);
    asm volatile("s_barrier" ::: "memory");
    compute(cur);

#pragma unroll
    for (int j = 0; j < 4; j++) {
        const int n = n0 + wn + j * 16 + ln;
        const float bias = b1[n];
#pragma unroll
        for (int i = 0; i < 4; i++) {
#pragma unroll
            for (int r = 0; r < 4; r++) {
                const int m = m0 + wm + i * 16 + quad * 4 + r;
                float x = acc[i][j][r] + bias;
                if (ACT == 1) x = fmaxf(x, 0.f);
                C[(size_t)m * N + n] = f2bf(x);
            }
        }
    }
}

// ---------- prep ----------
// wt0/wt1: f16 pair-pack [k2][u][8] f16:
//   8 = {wi(2k2),wi(2k2+1), wf(2k2),wf(2k2+1), wg(2k2),wg(2k2+1), wo(2k2),wo(2k2+1)}
// -> uint4 per (k2,u) = 4 gate k-pairs, feeds v_dot2_f32_f16 directly.
struct PrepArgs {
    const float *Wfe, *Wih0, *Whh0, *bih0, *bhh0, *Wih1, *Whh1, *bih1, *bhh1;
    const float *Wf1, *Wf2, *Wm1, *Ws1, *Wm2, *Ws2;
    const float *bm1, *bs1;
    ushort_t *Wfe_b, *Wih0_b, *Wih1_b, *wt0, *wt1, *Wf1_b, *Wf2_b, *Wms_b;
    float *W2t, *bias0s, *bias1s, *bms;
};
__global__ __launch_bounds__(256) void prep_k(PrepArgs a)
{
    const int idx = blockIdx.x * 256 + threadIdx.x;
    const int stride = gridDim.x * 256;
    for (int e = idx; e < 65536; e += stride)  a.Wfe_b[e]  = f2bf(a.Wfe[e]);
    for (int e = idx; e < 524288; e += stride) a.Wih0_b[e] = f2bf(a.Wih0[e]);   // (1024,512)
    for (int e = idx; e < 262144; e += stride) a.Wih1_b[e] = f2bf(a.Wih1[e]);   // (1024,256)
    for (int e = idx; e < 262144; e += stride) {              // wt0: f16 pair-pack (Whh0)
        const int k2 = e >> 11, r = e & 2047;
        const int u = r >> 3, t = r & 7;
        const int g = t >> 1, wh = t & 1;
        const int kk = (k2 << 1) + wh;
        a.wt0[e] = f2h(a.Whh0[(g * 256 + u) * 256 + kk]);
    }
    for (int e = idx; e < 262144; e += stride) {              // wt1: f16 pair-pack (Whh1)
        const int k2 = e >> 11, r = e & 2047;
        const int u = r >> 3, t = r & 7;
        const int g = t >> 1, wh = t & 1;
        const int kk = (k2 << 1) + wh;
        a.wt1[e] = f2h(a.Whh1[(g * 256 + u) * 256 + kk]);
    }
    for (int e = idx; e < 147456; e += stride) a.Wf1_b[e] = f2bf(a.Wf1[e]);
    for (int e = idx; e < 131072; e += stride) a.Wf2_b[e] = f2bf(a.Wf2[e]);
    for (int e = idx; e < 524288; e += stride) {              // Wms_b: (1024,512) = [Wm1; Ws1]
        const int n = e >> 9, k = e & 511;
        a.Wms_b[e] = f2bf((n < 512) ? a.Wm1[n * 512 + k] : a.Ws1[(n - 512) * 512 + k]);
    }
    for (int e = idx; e < 32768; e += stride) {               // W2t: (512,64) k-major f32
        const int k = e >> 6, c = e & 63;
        a.W2t[e] = (c < 32) ? a.Wm2[c * 512 + k] : a.Ws2[(c - 32) * 512 + k];
    }
    for (int e = idx; e < 1024; e += stride) {
        a.bias0s[e] = a.bih0[e] + a.bhh0[e];
        a.bias1s[e] = a.bih1[e] + a.bhh1[e];
        a.bms[e]    = (e < 512) ? a.bm1[e] : a.bs1[e - 512];
    }
}

// ---------- persistent LSTM scan: hybrid VGPR+LDS weight residency ----------
// R5 post-mortem: per-SIMD VGPR pool = 512 regs; wr[64] (256 regs) + working set
// at 2 waves/SIMD = 640 regs -> compiler spilled weights to SCRATCH, reloaded
// every step (VGPR_Count=128, WRITE_SIZE 3x, 2.9 us/step vs 0.85 VALU floor).
// Fix: 48 quads/thread in VGPRs (192 regs; __launch_bounds__(512,2) enforces
// <=256 total, no scratch) + 16 quads/thread parked in LDS (128 KB, written
// once, read back 16x ds_read_b128/step: ~1.1k cyc/CU/step, under the 2048-cyc
// VALU wall). LDS here is deliberate manual spill space with known cost.
// xs padded to 264 (row stride 528 B -> +4 bank offset) to kill R5's 3.3e7
// bank conflicts (256-elem rows put both batch rows on the same banks).
struct ScanArgs {
    const ushort_t* xg;      // (nsteps*512, 1024) bf16, gate order {i,f,g,o}x256
    const int*      dones;   // (257,512) int32, absolute t indexing
    const ushort_t* wt;      // f16 pair-packed recurrent weights [k2][u][8]
    ushort_t*       hout;    // bf16 h stream: (nsteps*512, 256), chunk-local s indexing
    float*          hst;     // persistent h (512*256 f32)
    float*          cst;     // persistent c (512*256 f32)
    int jc, nsteps, init;
};

#define DOTQ(W, H0, H1) do { \
    const h2v q0 = as_h2(H0), q1 = as_h2(H1); \
    p0i = dot2f(q0, as_h2((W).x), p0i); p0f = dot2f(q0, as_h2((W).y), p0f); \
    p0g = dot2f(q0, as_h2((W).z), p0g); p0o = dot2f(q0, as_h2((W).w), p0o); \
    p1i = dot2f(q1, as_h2((W).x), p1i); p1f = dot2f(q1, as_h2((W).y), p1f); \
    p1g = dot2f(q1, as_h2((W).z), p1g); p1o = dot2f(q1, as_h2((W).w), p1o); \
} while (0)

__global__ __launch_bounds__(512, 2) void scan_r_k(ScanArgs a)
{
    __shared__ __align__(16) ushort_t wlds[2][16][256][8];   // 128 KB weight parking
    __shared__ __align__(16) _Float16 xs[2][2][264];         // [phase][row][unit], padded
    const int tid = threadIdx.x;
    const int r = tid & 1, u = tid >> 1;
    const int b = blockIdx.x * 2 + r;
    float h = a.init ? 0.f : a.hst[b * 256 + u];
    float c = a.init ? 0.f : a.cst[b * 256 + u];

    // preload: 48 quads -> VGPRs, 16 quads -> LDS (both private to this thread)
    const ushort_t* wtu = a.wt + ((size_t)(r * 64) << 11) + 8 * u;
    uint4 wr[48];
#pragma unroll
    for (int j = 0; j < 48; ++j)
        wr[j] = *(const uint4*)(wtu + ((size_t)j << 11));
#pragma unroll
    for (int j = 0; j < 16; ++j)
        *(uint4*)&wlds[r][j][u][0] = *(const uint4*)(wtu + ((size_t)(48 + j) << 11));

    const int ks = r * 128;   // h-index base of this thread's k-half
    int ph = 0;
    float mval = 1.f - (float)a.dones[(size_t)a.jc * 512 + b];

    for (int sst = 0; sst < a.nsteps; ++sst) {
        xs[ph][r][u] = (_Float16)(h * mval);
        const float cold = c * mval;
        // prefetch next step's done mask (consumed next iteration)
        float mnext = 0.f;
        if (sst + 1 < a.nsteps)
            mnext = 1.f - (float)a.dones[(size_t)(a.jc + sst + 1) * 512 + b];
        // issue xg gate loads now; consumed after the dot loop
        const size_t base = ((size_t)sst * 512 + b) * 1024;
        const ushort_t g0 = a.xg[base + u];
        const ushort_t g1 = a.xg[base + 256 + u];
        const ushort_t g2 = a.xg[base + 512 + u];
        const ushort_t g3 = a.xg[base + 768 + u];
        __syncthreads();

        float p0i = 0.f, p0f = 0.f, p0g = 0.f, p0o = 0.f;   // row 0 partial (this k-half)
        float p1i = 0.f, p1f = 0.f, p1g = 0.f, p1o = 0.f;   // row 1 partial (this k-half)
        // quads 0..47 from VGPR
#pragma unroll
        for (int jj = 0; jj < 12; ++jj) {
            const uint4 h0 = *(const uint4*)&xs[ph][0][ks + jj * 8];
            const uint4 h1 = *(const uint4*)&xs[ph][1][ks + jj * 8];
            DOTQ(wr[jj * 4 + 0], h0.x, h1.x);
            DOTQ(wr[jj * 4 + 1], h0.y, h1.y);
            DOTQ(wr[jj * 4 + 2], h0.z, h1.z);
            DOTQ(wr[jj * 4 + 3], h0.w, h1.w);
        }
        // quads 48..63 from LDS parking
#pragma unroll
        for (int jj = 12; jj < 16; ++jj) {
            const uint4 h0 = *(const uint4*)&xs[ph][0][ks + jj * 8];
            const uint4 h1 = *(const uint4*)&xs[ph][1][ks + jj * 8];
            const uint4 w0 = *(const uint4*)&wlds[r][(jj - 12) * 4 + 0][u][0];
            const uint4 w1 = *(const uint4*)&wlds[r][(jj - 12) * 4 + 1][u][0];
            const uint4 w2 = *(const uint4*)&wlds[r][(jj - 12) * 4 + 2][u][0];
            const uint4 w3 = *(const uint4*)&wlds[r][(jj - 12) * 4 + 3][u][0];
            DOTQ(w0, h0.x, h1.x);
            DOTQ(w1, h0.y, h1.y);
            DOTQ(w2, h0.z, h1.z);
            DOTQ(w3, h0.w, h1.w);
        }

        // exchange other-half partials with partner lane (tid^1, same wave)
        const float s0 = (r == 0) ? p1i : p0i;
        const float s1 = (r == 0) ? p1f : p0f;
        const float s2 = (r == 0) ? p1g : p0g;
        const float s3 = (r == 0) ? p1o : p0o;
        const float o0 = __shfl_xor(s0, 1);
        const float o1 = __shfl_xor(s1, 1);
        const float o2 = __shfl_xor(s2, 1);
        const float o3 = __shfl_xor(s3, 1);

        const float ai  = ((r == 0) ? p0i : p1i) + o0 + bf2f(g0);
        const float af2 = ((r == 0) ? p0f : p1f) + o1 + bf2f(g1);
        const float ag  = ((r == 0) ? p0g : p1g) + o2 + bf2f(g2);
        const float ao  = ((r == 0) ? p0o : p1o) + o3 + bf2f(g3);

        const float c2 = fsigm(af2) * cold + fsigm(ai) * ftanh(ag);
        const float h2 = fsigm(ao) * ftanh(c2);
        c = c2; h = h2;
        a.hout[((size_t)sst * 512 + b) * 256 + u] = f2bf(h2);
        mval = mnext;
        ph ^= 1;
    }
    a.hst[b * 256 + u] = h;
    a.cst[b * 256 + u] = c;
}

// ---------- forward loss + intrinsic reward (row-chunked), f32 out ----------
__global__ __launch_bounds__(256) void fl_k(const ushort_t* __restrict__ pn,
                                            const ushort_t* __restrict__ outs,
                                            float* __restrict__ out, float* __restrict__ acc,
                                            int r0, int out_size)
{
    __shared__ float bs[4];
    const int tid = threadIdx.x;
    const int w = tid >> 6, l = tid & 63;
    const size_t rl = (size_t)blockIdx.x * 4 + w;
    const size_t rg = rl + r0;
    const ushort_t* p = pn + rl * 256;
    const ushort_t* q = outs + (rg + 512) * 256;   // next_state_features = outs[t+1]
    float s = 0.f;
#pragma unroll
    for (int i = 0; i < 4; i++) {
        const float d = bf2f(p[l + i * 64]) - bf2f(q[l + i * 64]);
        s += d * d;
    }
#pragma unroll
    for (int off = 32; off > 0; off >>= 1) s += __shfl_down(s, off);
    if (l == 0) { if ((long long)(2 + rg) < out_size) out[2 + rg] = s; bs[w] = s; }
    __syncthreads();
    if (tid == 0) atomicAdd(acc, bs[0] + bs[1] + bs[2] + bs[3]);
}

// ---------- fused mu/std heads + inverse loss (row-chunked), packed msh ----------
__global__ __launch_bounds__(256) void musd_k(
    const ushort_t* __restrict__ msh,    // (rows, 1024): [mh | sh]
    const float* __restrict__ W2t, const float* __restrict__ bm2,
    const float* __restrict__ bs2, const float* __restrict__ action,
    float* __restrict__ acc, int r0)
{
    __shared__ __align__(16) ushort_t mhs[8][512];
    __shared__ __align__(16) ushort_t shs[8][512];
    __shared__ float red[256];
    const int tid = threadIdx.x;
    const size_t rl0 = (size_t)blockIdx.x * 8;
    for (int i = tid; i < 512; i += 256) {
        const int row = i >> 6, c = (i & 63) * 8;
        *(uint4*)&mhs[row][c] = *(const uint4*)&msh[(rl0 + row) * 1024 + c];
        *(uint4*)&shs[row][c] = *(const uint4*)&msh[(rl0 + row) * 1024 + 512 + c];
    }
    __syncthreads();
    const int row = tid >> 5, c = tid & 31;
    float am = bm2[c], asv = bs2[c];
    for (int k = 0; k < 512; k += 8) {
#pragma unroll
        for (int e = 0; e < 8; e++) {
            const float wm = W2t[(k + e) * 64 + c];
            const float wsv = W2t[(k + e) * 64 + 32 + c];
            am  += bf2f(mhs[row][k + e]) * wm;
            asv += bf2f(shs[row][k + e]) * wsv;
        }
    }
    const float mu = ftanh(am);
    const float sp = fmaxf(asv, 0.f) + log1pf(__expf(-fabsf(asv)));   // softplus
    const float a  = action[(rl0 + r0 + row) * 32 + c];
    const float z  = (a - mu) / sp;
    red[tid] = 0.5f * z * z + __logf(sp) + 0.918938533204672741f;     // -log_prob
    __syncthreads();
    for (int s = 128; s > 0; s >>= 1) { if (tid < s) red[tid] += red[tid + s]; __syncthreads(); }
    if (tid == 0) atomicAdd(acc, red[0]);
}

// ---------- finalize: scalar losses + hidden copy-out (f32) ----------
__global__ __launch_bounds__(256) void fin_k(const float* __restrict__ acc,
                                             const float* __restrict__ h0st,
                                             const float* __restrict__ h1st,
                                             const float* __restrict__ c0st,
                                             const float* __restrict__ c1st,
                                             float* __restrict__ out, int out_size)
{
    const size_t idx = (size_t)blockIdx.x * 256 + threadIdx.x;
    if (idx == 0 && out_size > 0) out[0] = acc[0] / 33554432.f;   // mean over 256*512*256
    if (idx == 1 && out_size > 1) out[1] = acc[1] / 4194304.f;    // mean over 256*512*32
    if (idx < 524288) {
        const int which = (int)(idx >> 17);
        const int local = (int)(idx & 131071);
        float v;
        if      (which == 0) v = h0st[local];
        else if (which == 1) v = h1st[local];
        else if (which == 2) v = c0st[local];
        else                 v = c1st[local];
        const size_t o = 2 + 131072 + idx;
        if ((long long)o < out_size) out[o] = v;
    }
}

extern "C" void kernel_launch(void* const* d_in, const int* in_sizes, int n_in,
                              void* d_out, int out_size, void* d_ws, size_t ws_size,
                              hipStream_t stream)
{
    const float* states = (const float*)d_in[0];
    const float* action = (const float*)d_in[1];
    const int*   dones  = (const int*)d_in[2];
    const float* Wfe  = (const float*)d_in[3];
    const float* bfe  = (const float*)d_in[4];
    const float* Wih0 = (const float*)d_in[5];
    const float* Whh0 = (const float*)d_in[6];
    const float* bih0 = (const float*)d_in[7];
    const float* bhh0 = (const float*)d_in[8];
    const float* Wih1 = (const float*)d_in[9];
    const float* Whh1 = (const float*)d_in[10];
    const float* bih1 = (const float*)d_in[11];
    const float* bhh1 = (const float*)d_in[12];
    const float* Wf1  = (const float*)d_in[13];
    const float* bf1  = (const float*)d_in[14];
    const float* Wf2  = (const float*)d_in[15];
    const float* bf2  = (const float*)d_in[16];
    const float* Wm1  = (const float*)d_in[17];
    const float* bm1  = (const float*)d_in[18];
    const float* Wm2  = (const float*)d_in[19];
    const float* bm2  = (const float*)d_in[20];
    const float* Ws1  = (const float*)d_in[21];
    const float* bs1  = (const float*)d_in[22];
    const float* Ws2  = (const float*)d_in[23];
    const float* bs2  = (const float*)d_in[24];

    // ---------- workspace layout (persistent region) ----------
    char* ws = (char*)d_ws;
    size_t off = 0;
    ushort_t* outs    = (ushort_t*)(ws + off); off += 67371008;  // 257*512*256 bf16
    float*    h0st    = (float*)(ws + off);    off += 524288;
    float*    c0st    = (float*)(ws + off);    off += 524288;
    float*    h1st    = (float*)(ws + off);    off += 524288;
    float*    c1st    = (float*)(ws + off);    off += 524288;
    ushort_t* wt0     = (ushort_t*)(ws + off); off += 524288;    // f16 pairs [k2][u][8]
    ushort_t* wt1     = (ushort_t*)(ws + off); off += 524288;    // f16 pairs [k2][u][8]
    ushort_t* Wfe_b   = (ushort_t*)(ws + off); off += 131072;
    ushort_t* Wih0_b  = (ushort_t*)(ws + off); off += 1048576;
    ushort_t* Wih1_b  = (ushort_t*)(ws + off); off += 524288;
    ushort_t* Wf1_b   = (ushort_t*)(ws + off); off += 294912;
    ushort_t* Wf2_b   = (ushort_t*)(ws + off); off += 262144;
    ushort_t* Wms_b   = (ushort_t*)(ws + off); off += 1048576;
    float*    W2t     = (float*)(ws + off);    off += 131072;
    float*    bias0s  = (float*)(ws + off);    off += 4096;
    float*    bias1s  = (float*)(ws + off);    off += 4096;
    float*    bms     = (float*)(ws + off);    off += 4096;
    float*    accp    = (float*)(ws + off);    off += 256;
    char*     S       = ws + off;              // chunk scratch
    const size_t avail = (ws_size > off) ? (ws_size - off) : 0;

    // scan-phase chunk with buffer overlay:
    //   xgck: TC x 1 MB   (xg0, then xg1 reuses it — xg0 dead after scan0)
    //   fck : TC x 512 KB (feats, then h0s overlays — feats dead after xg0 GEMM)
    const size_t STEP_B = 1572864;
    int TC = (int)(avail / STEP_B);
    if (TC > 257) TC = 257;
    if (TC < 1)  TC = 1;
    // head-phase chunk: per row ph(1024)+pn(512)+msh(2048) = 3584 B; cap 24576 rows (~88 MB)
    long long rc = (long long)(avail / 3584) & ~127LL;
    if (rc > 24576) rc = 24576;
    if (rc < 128)   rc = 128;
    const int RC = (int)rc;

    hipMemsetAsync(accp, 0, 256, stream);

    PrepArgs pa{ Wfe, Wih0, Whh0, bih0, bhh0, Wih1, Whh1, bih1, bhh1,
                 Wf1, Wf2, Wm1, Ws1, Wm2, Ws2, bm1, bs1,
                 Wfe_b, Wih0_b, Wih1_b, wt0, wt1, Wf1_b, Wf2_b, Wms_b,
                 W2t, bias0s, bias1s, bms };
    prep_k<<<512, 256, 0, stream>>>(pa);

    // ---------- scan phase ----------
    ushort_t* xgck = (ushort_t*)S;
    ushort_t* fck  = (ushort_t*)(S + (size_t)TC * 1048576);
    for (int jc = 0; jc < 257; jc += TC) {
        const int nsteps = (257 - jc < TC) ? (257 - jc) : TC;
        // feats = relu(states_chunk @ Wfe^T + bfe)      [N=512, K=128]
        gemm_k<0, 1, float, float><<<dim3(nsteps * 4, 4), 256, 0, stream>>>(
            states + (size_t)jc * 512 * 128, nullptr, Wfe_b, bfe, fck, 128, 512);
        // xg0 = feats @ Wih0^T + (bih0 + bhh0)          [N=1024, K=512]
        gemm_k<0, 0, ushort_t, ushort_t><<<dim3(nsteps * 4, 8), 256, 0, stream>>>(
            fck, nullptr, Wih0_b, bias0s, xgck, 512, 1024);
        // layer-0 scan — h0s overlays feats region
        ScanArgs sa0{ xgck, dones, wt0, fck, h0st, c0st, jc, nsteps, (jc == 0) ? 1 : 0 };
        scan_r_k<<<256, 512, 0, stream>>>(sa0);
        // xg1 = h0s @ Wih1^T + (bih1 + bhh1)            [N=1024, K=256] — xg1 reuses xgck
        gemm_k<0, 0, ushort_t, ushort_t><<<dim3(nsteps * 4, 8), 256, 0, stream>>>(
            fck, nullptr, Wih1_b, bias1s, xgck, 256, 1024);
        // layer-1 scan
        ScanArgs sa1{ xgck, dones, wt1, outs + (size_t)jc * 131072,
                      h1st, c1st, jc, nsteps, (jc == 0) ? 1 : 0 };
        scan_r_k<<<256, 512, 0, stream>>>(sa1);
    }

    // ---------- head phase (row-chunked, L3-resident chunks) ----------
    for (int r0 = 0; r0 < M_SEQ; r0 += RC) {
        const int rows = (M_SEQ - r0 < RC) ? (M_SEQ - r0) : RC;
        ushort_t* ph  = (ushort_t*)S;
        ushort_t* pn  = (ushort_t*)(S + (size_t)rows * 1024);
        ushort_t* msh = (ushort_t*)(S + (size_t)rows * 1536);
        // pred_hidden = relu([sf, action] @ Wf1^T + bf1)  [N=512, K=288]
        gemm_k<1, 1, ushort_t, float><<<dim3(rows / 128, 4), 256, 0, stream>>>(
            outs + (size_t)r0 * 256, action + (size_t)r0 * 32, Wf1_b, bf1, ph, 288, 512);
        // pred_next = pred_hidden @ Wf2^T + bf2           [N=256, K=512]
        gemm_k<0, 0, ushort_t, ushort_t><<<dim3(rows / 128, 2), 256, 0, stream>>>(
            ph, nullptr, Wf2_b, bf2, pn, 512, 256);
        // forward loss + intrinsic reward
        fl_k<<<rows / 4, 256, 0, stream>>>(pn, outs, (float*)d_out, accp, r0, out_size);
        // msh = relu([sf, pred_next] @ [Wm1;Ws1]^T + [bm1;bs1])  [N=1024, K=512]
        gemm_k<2, 1, ushort_t, ushort_t><<<dim3(rows / 128, 8), 256, 0, stream>>>(
            outs + (size_t)r0 * 256, pn, Wms_b, bms, msh, 512, 1024);
        // mu/std heads + inverse loss
        musd_k<<<rows / 8, 256, 0, stream>>>(msh, W2t, bm2, bs2, action, accp + 1, r0);
    }

    // scalars + hidden
    fin_k<<<2048, 256, 0, stream>>>(accp, h0st, h1st, c0st, c1st, (float*)d_out, out_size);
}

// Round 7
// 3413.249 us; speedup vs baseline: 1.4577x; 1.0157x over previous
//
#include <hip/hip_runtime.h>
#include <hip/hip_bf16.h>

typedef unsigned short ushort_t;
typedef unsigned int   uint_t;

// Problem constants: T1=257, B=512, SD=128, AD=32, HS=512, SF=256, L=2
#define M_ALL 131584   // 257*512
#define M_SEQ 131072   // 256*512

// ---------- helpers ----------
__device__ __forceinline__ float bf2f(ushort_t u) {
    union { uint_t i; float f; } v; v.i = ((uint_t)u) << 16; return v.f;
}
__device__ __forceinline__ ushort_t f2bf(float f) {
    union { float f; uint_t i; } v; v.f = f;
    uint_t r = v.i + 0x7FFFu + ((v.i >> 16) & 1u);
    return (ushort_t)(r >> 16);
}
__device__ __forceinline__ ushort_t f2h(float f) {
    union { _Float16 h; ushort_t u; } v; v.h = (_Float16)f; return v.u;
}
__device__ __forceinline__ float fsigm(float x) { return 1.f / (1.f + __expf(-x)); }
__device__ __forceinline__ float ftanh(float x) {
    x = fminf(15.f, fmaxf(-15.f, x));
    float e = __expf(2.f * x);
    return (e - 1.f) / (e + 1.f);
}

typedef __attribute__((ext_vector_type(8))) short  bfrag;   // 8 x bf16
typedef __attribute__((ext_vector_type(4))) float  ffrag;   // 4 x f32 accum
typedef __attribute__((ext_vector_type(2))) _Float16 h2v;   // 2 x f16

__device__ __forceinline__ h2v as_h2(uint_t x) {
    union { uint_t u; h2v h; } v; v.u = x; return v.h;
}
// f16 pair dot with f32 accumulate: v_dot2_f32_f16 (proven R2-R6)
__device__ __forceinline__ float dot2f(h2v a, h2v b, float acc) {
#if __has_builtin(__builtin_amdgcn_fdot2)
    return __builtin_amdgcn_fdot2(a, b, acc, false);
#else
    return acc + (float)a.x * (float)b.x + (float)a.y * (float)b.y;
#endif
}

// async global->LDS, 16B per lane; dest base must be wave-uniform (lane*16 auto)
typedef const __attribute__((address_space(1))) unsigned int as1_u32;
typedef __attribute__((address_space(3))) unsigned int as3_u32;
__device__ __forceinline__ void gload16(const void* g, void* l) {
    __builtin_amdgcn_global_load_lds((as1_u32*)g, (as3_u32*)l, 16, 0, 0);
}

// manual stage of 8 elements into LDS as bf16 (f32 source converts)
__device__ __forceinline__ void stage8(const float* p, ushort_t* dst) {
    const float4 a = *(const float4*)p;
    const float4 b = *(const float4*)(p + 4);
    bfrag v;
    v[0] = (short)f2bf(a.x); v[1] = (short)f2bf(a.y);
    v[2] = (short)f2bf(a.z); v[3] = (short)f2bf(a.w);
    v[4] = (short)f2bf(b.x); v[5] = (short)f2bf(b.y);
    v[6] = (short)f2bf(b.z); v[7] = (short)f2bf(b.w);
    *(bfrag*)dst = v;
}

// ---------- 128x128-tile bf16 MFMA GEMM, counted-vmcnt 2-phase pipeline ----------
// C = act(A @ W^T + bias), C bf16, W bf16, bias f32.
// R7: 1D grid + XCD-chunked swizzle, COLUMN fastest. Old dim3(row,col) grid put
// the 8 col-siblings of one A row-tile a full sweep apart -> A re-fetched
// ncol x (xg0: 1.08 GB). Now l = (bid&7)*(nwg/8)+(bid>>3): consecutive logical
// tiles = col-fastest AND each mod-8 class (one XCD under round-robin dispatch)
// owns a contiguous chunk -> A-tile fetched into one L2 once; W stays L2-resident.
// AMODE 0: plain A1 (stride K)
// AMODE 1: k<256 -> A1 stride 256 ; k>=256 -> A2 stride 32  (x = [sf, action]), A2 f32
// AMODE 2: k<256 -> A1 stride 256 ; k>=256 -> A2 stride 256 (xi = [sf, pred_next])
template<int AMODE, int ACT, typename TA1, typename TA2>
__global__ __launch_bounds__(256) void gemm_k(
    const TA1* __restrict__ A1, const TA2* __restrict__ A2,
    const ushort_t* __restrict__ W, const float* __restrict__ b1,
    ushort_t* __restrict__ C, int K, int N)
{
    __shared__ __align__(16) ushort_t As[2][128][32];
    __shared__ __align__(16) ushort_t Ws[2][128][32];

    const int tid  = threadIdx.x;
    // XCD-chunked 1D swizzle (nwg always divisible by 8 in this launch set)
    const int nwg  = (int)gridDim.x;
    const int p    = (int)blockIdx.x;
    const int l    = (p & 7) * (nwg >> 3) + (p >> 3);
    const int ncol = N >> 7;                 // 2, 4 or 8 (power of 2)
    const int ncs  = 31 - __clz(ncol);
    const int m0   = (l >> ncs) * 128;
    const int n0   = (l & (ncol - 1)) * 128;
    const int lane = tid & 63;
    const int wv   = tid >> 6;
    const int wm   = (wv & 1) * 64;
    const int wn   = (wv >> 1) * 64;
    const int quad = lane >> 4;
    const int ln   = lane & 15;

    ffrag acc[4][4];
#pragma unroll
    for (int i = 0; i < 4; i++)
#pragma unroll
        for (int j = 0; j < 4; j++) acc[i][j] = (ffrag){0.f, 0.f, 0.f, 0.f};

    const int grow = lane >> 2;        // row within a 16-row gload group
    const int gcol = (lane & 3) * 8;   // element col 0,8,16,24
    const int arow = tid >> 2;         // manual-stage row (0..63; +64 via rr)
    const int acol = (tid & 3) * 8;

    auto stage = [&](int buf, int k0) {
#pragma unroll
        for (int c = 0; c < 2; c++) {
            const int rb = (wv << 5) + (c << 4);
            gload16(W + (size_t)(n0 + rb + grow) * K + k0 + gcol, &Ws[buf][rb][0]);
        }
        if constexpr (sizeof(TA1) == 4) {
#pragma unroll
            for (int rr = 0; rr < 2; rr++)
                stage8((const float*)A1 + (size_t)(m0 + arow + rr * 64) * K + k0 + acol,
                       &As[buf][arow + rr * 64][acol]);
        } else {
            if (AMODE == 1 && sizeof(TA2) == 4 && k0 >= 256) {
#pragma unroll
                for (int rr = 0; rr < 2; rr++)
                    stage8((const float*)A2 + (size_t)(m0 + arow + rr * 64) * 32 + (k0 - 256) + acol,
                           &As[buf][arow + rr * 64][acol]);
            } else {
#pragma unroll
                for (int c = 0; c < 2; c++) {
                    const int rb = (wv << 5) + (c << 4);
                    const int r  = rb + grow;
                    const ushort_t* src;
                    if (AMODE == 0)     src = (const ushort_t*)A1 + (size_t)(m0 + r) * K + k0 + gcol;
                    else if (k0 < 256)  src = (const ushort_t*)A1 + (size_t)(m0 + r) * 256 + k0 + gcol;
                    else                src = (const ushort_t*)A2 + (size_t)(m0 + r) * 256 + (k0 - 256) + gcol; // AMODE 2
                    gload16(src, &As[buf][rb][0]);
                }
            }
        }
    };
    auto compute = [&](int buf) {
        bfrag af[4], bfv[4];
#pragma unroll
        for (int i = 0; i < 4; i++) af[i]  = *(const bfrag*)&As[buf][wm + i * 16 + ln][quad * 8];
#pragma unroll
        for (int j = 0; j < 4; j++) bfv[j] = *(const bfrag*)&Ws[buf][wn + j * 16 + ln][quad * 8];
#pragma unroll
        for (int i = 0; i < 4; i++)
#pragma unroll
            for (int j = 0; j < 4; j++)
                acc[i][j] = __builtin_amdgcn_mfma_f32_16x16x32_bf16(af[i], bfv[j], acc[i][j], 0, 0, 0);
    };

    stage(0, 0);
    int cur = 0;
    for (int k0 = 32; k0 < K; k0 += 32) {
        stage(cur ^ 1, k0);   // issue next tile; stays in flight through compute
        if constexpr (sizeof(TA1) == 4) {
            asm volatile("s_waitcnt vmcnt(2) lgkmcnt(0)" ::: "memory");
        } else if constexpr (AMODE == 1 && sizeof(TA2) == 4) {
            if (k0 >= 256) asm volatile("s_waitcnt vmcnt(2) lgkmcnt(0)" ::: "memory");
            else           asm volatile("s_waitcnt vmcnt(4)" ::: "memory");
        } else {
            asm volatile("s_waitcnt vmcnt(4)" ::: "memory");
        }
        __builtin_amdgcn_sched_barrier(0);
        asm volatile("s_barrier" ::: "memory");
        compute(cur);
        asm volatile("s_waitcnt lgkmcnt(0)" ::: "memory");
        __builtin_amdgcn_sched_barrier(0);
        asm volatile("s_barrier" ::: "memory");
        cur ^= 1;
    }
    asm volatile("s_waitcnt vmcnt(0) lgkmcnt(0)" ::: "memory");
    __builtin_amdgcn_sched_barrier(0);
    asm volatile("s_barrier" ::: "memory");
    compute(cur);

#pragma unroll
    for (int j = 0; j < 4; j++) {
        const int n = n0 + wn + j * 16 + ln;
        const float bias = b1[n];
#pragma unroll
        for (int i = 0; i < 4; i++) {
#pragma unroll
            for (int r = 0; r < 4; r++) {
                const int m = m0 + wm + i * 16 + quad * 4 + r;
                float x = acc[i][j][r] + bias;
                if (ACT == 1) x = fmaxf(x, 0.f);
                C[(size_t)m * N + n] = f2bf(x);
            }
        }
    }
}

// ---------- prep ----------
// wt0/wt1: f16 pair-pack [k2][u][8] f16:
//   8 = {wi(2k2),wi(2k2+1), wf(2k2),wf(2k2+1), wg(2k2),wg(2k2+1), wo(2k2),wo(2k2+1)}
// -> uint4 per (k2,u) = 4 gate k-pairs, feeds v_dot2_f32_f16 directly.
struct PrepArgs {
    const float *Wfe, *Wih0, *Whh0, *bih0, *bhh0, *Wih1, *Whh1, *bih1, *bhh1;
    const float *Wf1, *Wf2, *Wm1, *Ws1, *Wm2, *Ws2;
    const float *bm1, *bs1;
    ushort_t *Wfe_b, *Wih0_b, *Wih1_b, *wt0, *wt1, *Wf1_b, *Wf2_b, *Wms_b;
    float *W2t, *bias0s, *bias1s, *bms;
};
__global__ __launch_bounds__(256) void prep_k(PrepArgs a)
{
    const int idx = blockIdx.x * 256 + threadIdx.x;
    const int stride = gridDim.x * 256;
    for (int e = idx; e < 65536; e += stride)  a.Wfe_b[e]  = f2bf(a.Wfe[e]);
    for (int e = idx; e < 524288; e += stride) a.Wih0_b[e] = f2bf(a.Wih0[e]);   // (1024,512)
    for (int e = idx; e < 262144; e += stride) a.Wih1_b[e] = f2bf(a.Wih1[e]);   // (1024,256)
    for (int e = idx; e < 262144; e += stride) {              // wt0: f16 pair-pack (Whh0)
        const int k2 = e >> 11, r = e & 2047;
        const int u = r >> 3, t = r & 7;
        const int g = t >> 1, wh = t & 1;
        const int kk = (k2 << 1) + wh;
        a.wt0[e] = f2h(a.Whh0[(g * 256 + u) * 256 + kk]);
    }
    for (int e = idx; e < 262144; e += stride) {              // wt1: f16 pair-pack (Whh1)
        const int k2 = e >> 11, r = e & 2047;
        const int u = r >> 3, t = r & 7;
        const int g = t >> 1, wh = t & 1;
        const int kk = (k2 << 1) + wh;
        a.wt1[e] = f2h(a.Whh1[(g * 256 + u) * 256 + kk]);
    }
    for (int e = idx; e < 147456; e += stride) a.Wf1_b[e] = f2bf(a.Wf1[e]);
    for (int e = idx; e < 131072; e += stride) a.Wf2_b[e] = f2bf(a.Wf2[e]);
    for (int e = idx; e < 524288; e += stride) {              // Wms_b: (1024,512) = [Wm1; Ws1]
        const int n = e >> 9, k = e & 511;
        a.Wms_b[e] = f2bf((n < 512) ? a.Wm1[n * 512 + k] : a.Ws1[(n - 512) * 512 + k]);
    }
    for (int e = idx; e < 32768; e += stride) {               // W2t: (512,64) k-major f32
        const int k = e >> 6, c = e & 63;
        a.W2t[e] = (c < 32) ? a.Wm2[c * 512 + k] : a.Ws2[(c - 32) * 512 + k];
    }
    for (int e = idx; e < 1024; e += stride) {
        a.bias0s[e] = a.bih0[e] + a.bhh0[e];
        a.bias1s[e] = a.bih1[e] + a.bhh1[e];
        a.bms[e]    = (e < 512) ? a.bm1[e] : a.bs1[e - 512];
    }
}

// ---------- persistent LSTM scan: hybrid VGPR+LDS weight residency (R6-proven) ----------
struct ScanArgs {
    const ushort_t* xg;      // (nsteps*512, 1024) bf16, gate order {i,f,g,o}x256
    const int*      dones;   // (257,512) int32, absolute t indexing
    const ushort_t* wt;      // f16 pair-packed recurrent weights [k2][u][8]
    ushort_t*       hout;    // bf16 h stream: (nsteps*512, 256), chunk-local s indexing
    float*          hst;     // persistent h (512*256 f32)
    float*          cst;     // persistent c (512*256 f32)
    int jc, nsteps, init;
};

#define DOTQ(W, H0, H1) do { \
    const h2v q0 = as_h2(H0), q1 = as_h2(H1); \
    p0i = dot2f(q0, as_h2((W).x), p0i); p0f = dot2f(q0, as_h2((W).y), p0f); \
    p0g = dot2f(q0, as_h2((W).z), p0g); p0o = dot2f(q0, as_h2((W).w), p0o); \
    p1i = dot2f(q1, as_h2((W).x), p1i); p1f = dot2f(q1, as_h2((W).y), p1f); \
    p1g = dot2f(q1, as_h2((W).z), p1g); p1o = dot2f(q1, as_h2((W).w), p1o); \
} while (0)

__global__ __launch_bounds__(512, 2) void scan_r_k(ScanArgs a)
{
    __shared__ __align__(16) ushort_t wlds[2][16][256][8];   // 128 KB weight parking
    __shared__ __align__(16) _Float16 xs[2][2][264];         // [phase][row][unit], padded
    const int tid = threadIdx.x;
    const int r = tid & 1, u = tid >> 1;
    const int b = blockIdx.x * 2 + r;
    float h = a.init ? 0.f : a.hst[b * 256 + u];
    float c = a.init ? 0.f : a.cst[b * 256 + u];

    // preload: 48 quads -> VGPRs, 16 quads -> LDS (both private to this thread)
    const ushort_t* wtu = a.wt + ((size_t)(r * 64) << 11) + 8 * u;
    uint4 wr[48];
#pragma unroll
    for (int j = 0; j < 48; ++j)
        wr[j] = *(const uint4*)(wtu + ((size_t)j << 11));
#pragma unroll
    for (int j = 0; j < 16; ++j)
        *(uint4*)&wlds[r][j][u][0] = *(const uint4*)(wtu + ((size_t)(48 + j) << 11));

    const int ks = r * 128;   // h-index base of this thread's k-half
    int ph = 0;
    float mval = 1.f - (float)a.dones[(size_t)a.jc * 512 + b];

    for (int sst = 0; sst < a.nsteps; ++sst) {
        xs[ph][r][u] = (_Float16)(h * mval);
        const float cold = c * mval;
        // prefetch next step's done mask (consumed next iteration)
        float mnext = 0.f;
        if (sst + 1 < a.nsteps)
            mnext = 1.f - (float)a.dones[(size_t)(a.jc + sst + 1) * 512 + b];
        // issue xg gate loads now; consumed after the dot loop
        const size_t base = ((size_t)sst * 512 + b) * 1024;
        const ushort_t g0 = a.xg[base + u];
        const ushort_t g1 = a.xg[base + 256 + u];
        const ushort_t g2 = a.xg[base + 512 + u];
        const ushort_t g3 = a.xg[base + 768 + u];
        __syncthreads();

        float p0i = 0.f, p0f = 0.f, p0g = 0.f, p0o = 0.f;   // row 0 partial (this k-half)
        float p1i = 0.f, p1f = 0.f, p1g = 0.f, p1o = 0.f;   // row 1 partial (this k-half)
        // quads 0..47 from VGPR
#pragma unroll
        for (int jj = 0; jj < 12; ++jj) {
            const uint4 h0 = *(const uint4*)&xs[ph][0][ks + jj * 8];
            const uint4 h1 = *(const uint4*)&xs[ph][1][ks + jj * 8];
            DOTQ(wr[jj * 4 + 0], h0.x, h1.x);
            DOTQ(wr[jj * 4 + 1], h0.y, h1.y);
            DOTQ(wr[jj * 4 + 2], h0.z, h1.z);
            DOTQ(wr[jj * 4 + 3], h0.w, h1.w);
        }
        // quads 48..63 from LDS parking
#pragma unroll
        for (int jj = 12; jj < 16; ++jj) {
            const uint4 h0 = *(const uint4*)&xs[ph][0][ks + jj * 8];
            const uint4 h1 = *(const uint4*)&xs[ph][1][ks + jj * 8];
            const uint4 w0 = *(const uint4*)&wlds[r][(jj - 12) * 4 + 0][u][0];
            const uint4 w1 = *(const uint4*)&wlds[r][(jj - 12) * 4 + 1][u][0];
            const uint4 w2 = *(const uint4*)&wlds[r][(jj - 12) * 4 + 2][u][0];
            const uint4 w3 = *(const uint4*)&wlds[r][(jj - 12) * 4 + 3][u][0];
            DOTQ(w0, h0.x, h1.x);
            DOTQ(w1, h0.y, h1.y);
            DOTQ(w2, h0.z, h1.z);
            DOTQ(w3, h0.w, h1.w);
        }

        // exchange other-half partials with partner lane (tid^1, same wave)
        const float s0 = (r == 0) ? p1i : p0i;
        const float s1 = (r == 0) ? p1f : p0f;
        const float s2 = (r == 0) ? p1g : p0g;
        const float s3 = (r == 0) ? p1o : p0o;
        const float o0 = __shfl_xor(s0, 1);
        const float o1 = __shfl_xor(s1, 1);
        const float o2 = __shfl_xor(s2, 1);
        const float o3 = __shfl_xor(s3, 1);

        const float ai  = ((r == 0) ? p0i : p1i) + o0 + bf2f(g0);
        const float af2 = ((r == 0) ? p0f : p1f) + o1 + bf2f(g1);
        const float ag  = ((r == 0) ? p0g : p1g) + o2 + bf2f(g2);
        const float ao  = ((r == 0) ? p0o : p1o) + o3 + bf2f(g3);

        const float c2 = fsigm(af2) * cold + fsigm(ai) * ftanh(ag);
        const float h2 = fsigm(ao) * ftanh(c2);
        c = c2; h = h2;
        a.hout[((size_t)sst * 512 + b) * 256 + u] = f2bf(h2);
        mval = mnext;
        ph ^= 1;
    }
    a.hst[b * 256 + u] = h;
    a.cst[b * 256 + u] = c;
}

// ---------- forward loss + intrinsic reward (row-chunked), f32 out ----------
__global__ __launch_bounds__(256) void fl_k(const ushort_t* __restrict__ pn,
                                            const ushort_t* __restrict__ outs,
                                            float* __restrict__ out, float* __restrict__ acc,
                                            int r0, int out_size)
{
    __shared__ float bs[4];
    const int tid = threadIdx.x;
    const int w = tid >> 6, l = tid & 63;
    const size_t rl = (size_t)blockIdx.x * 4 + w;
    const size_t rg = rl + r0;
    const ushort_t* p = pn + rl * 256;
    const ushort_t* q = outs + (rg + 512) * 256;   // next_state_features = outs[t+1]
    float s = 0.f;
#pragma unroll
    for (int i = 0; i < 4; i++) {
        const float d = bf2f(p[l + i * 64]) - bf2f(q[l + i * 64]);
        s += d * d;
    }
#pragma unroll
    for (int off = 32; off > 0; off >>= 1) s += __shfl_down(s, off);
    if (l == 0) { if ((long long)(2 + rg) < out_size) out[2 + rg] = s; bs[w] = s; }
    __syncthreads();
    if (tid == 0) atomicAdd(acc, bs[0] + bs[1] + bs[2] + bs[3]);
}

// ---------- fused mu/std heads + inverse loss (row-chunked), packed msh ----------
__global__ __launch_bounds__(256) void musd_k(
    const ushort_t* __restrict__ msh,    // (rows, 1024): [mh | sh]
    const float* __restrict__ W2t, const float* __restrict__ bm2,
    const float* __restrict__ bs2, const float* __restrict__ action,
    float* __restrict__ acc, int r0)
{
    __shared__ __align__(16) ushort_t mhs[8][512];
    __shared__ __align__(16) ushort_t shs[8][512];
    __shared__ float red[256];
    const int tid = threadIdx.x;
    const size_t rl0 = (size_t)blockIdx.x * 8;
    for (int i = tid; i < 512; i += 256) {
        const int row = i >> 6, c = (i & 63) * 8;
        *(uint4*)&mhs[row][c] = *(const uint4*)&msh[(rl0 + row) * 1024 + c];
        *(uint4*)&shs[row][c] = *(const uint4*)&msh[(rl0 + row) * 1024 + 512 + c];
    }
    __syncthreads();
    const int row = tid >> 5, c = tid & 31;
    float am = bm2[c], asv = bs2[c];
    for (int k = 0; k < 512; k += 8) {
#pragma unroll
        for (int e = 0; e < 8; e++) {
            const float wm = W2t[(k + e) * 64 + c];
            const float wsv = W2t[(k + e) * 64 + 32 + c];
            am  += bf2f(mhs[row][k + e]) * wm;
            asv += bf2f(shs[row][k + e]) * wsv;
        }
    }
    const float mu = ftanh(am);
    const float sp = fmaxf(asv, 0.f) + log1pf(__expf(-fabsf(asv)));   // softplus
    const float a  = action[(rl0 + r0 + row) * 32 + c];
    const float z  = (a - mu) / sp;
    red[tid] = 0.5f * z * z + __logf(sp) + 0.918938533204672741f;     // -log_prob
    __syncthreads();
    for (int s = 128; s > 0; s >>= 1) { if (tid < s) red[tid] += red[tid + s]; __syncthreads(); }
    if (tid == 0) atomicAdd(acc, red[0]);
}

// ---------- finalize: scalar losses + hidden copy-out (f32) ----------
__global__ __launch_bounds__(256) void fin_k(const float* __restrict__ acc,
                                             const float* __restrict__ h0st,
                                             const float* __restrict__ h1st,
                                             const float* __restrict__ c0st,
                                             const float* __restrict__ c1st,
                                             float* __restrict__ out, int out_size)
{
    const size_t idx = (size_t)blockIdx.x * 256 + threadIdx.x;
    if (idx == 0 && out_size > 0) out[0] = acc[0] / 33554432.f;   // mean over 256*512*256
    if (idx == 1 && out_size > 1) out[1] = acc[1] / 4194304.f;    // mean over 256*512*32
    if (idx < 524288) {
        const int which = (int)(idx >> 17);
        const int local = (int)(idx & 131071);
        float v;
        if      (which == 0) v = h0st[local];
        else if (which == 1) v = h1st[local];
        else if (which == 2) v = c0st[local];
        else                 v = c1st[local];
        const size_t o = 2 + 131072 + idx;
        if ((long long)o < out_size) out[o] = v;
    }
}

extern "C" void kernel_launch(void* const* d_in, const int* in_sizes, int n_in,
                              void* d_out, int out_size, void* d_ws, size_t ws_size,
                              hipStream_t stream)
{
    const float* states = (const float*)d_in[0];
    const float* action = (const float*)d_in[1];
    const int*   dones  = (const int*)d_in[2];
    const float* Wfe  = (const float*)d_in[3];
    const float* bfe  = (const float*)d_in[4];
    const float* Wih0 = (const float*)d_in[5];
    const float* Whh0 = (const float*)d_in[6];
    const float* bih0 = (const float*)d_in[7];
    const float* bhh0 = (const float*)d_in[8];
    const float* Wih1 = (const float*)d_in[9];
    const float* Whh1 = (const float*)d_in[10];
    const float* bih1 = (const float*)d_in[11];
    const float* bhh1 = (const float*)d_in[12];
    const float* Wf1  = (const float*)d_in[13];
    const float* bf1  = (const float*)d_in[14];
    const float* Wf2  = (const float*)d_in[15];
    const float* bf2  = (const float*)d_in[16];
    const float* Wm1  = (const float*)d_in[17];
    const float* bm1  = (const float*)d_in[18];
    const float* Wm2  = (const float*)d_in[19];
    const float* bm2  = (const float*)d_in[20];
    const float* Ws1  = (const float*)d_in[21];
    const float* bs1  = (const float*)d_in[22];
    const float* Ws2  = (const float*)d_in[23];
    const float* bs2  = (const float*)d_in[24];

    // ---------- workspace layout (persistent region) ----------
    char* ws = (char*)d_ws;
    size_t off = 0;
    ushort_t* outs    = (ushort_t*)(ws + off); off += 67371008;  // 257*512*256 bf16
    float*    h0st    = (float*)(ws + off);    off += 524288;
    float*    c0st    = (float*)(ws + off);    off += 524288;
    float*    h1st    = (float*)(ws + off);    off += 524288;
    float*    c1st    = (float*)(ws + off);    off += 524288;
    ushort_t* wt0     = (ushort_t*)(ws + off); off += 524288;    // f16 pairs [k2][u][8]
    ushort_t* wt1     = (ushort_t*)(ws + off); off += 524288;    // f16 pairs [k2][u][8]
    ushort_t* Wfe_b   = (ushort_t*)(ws + off); off += 131072;
    ushort_t* Wih0_b  = (ushort_t*)(ws + off); off += 1048576;
    ushort_t* Wih1_b  = (ushort_t*)(ws + off); off += 524288;
    ushort_t* Wf1_b   = (ushort_t*)(ws + off); off += 294912;
    ushort_t* Wf2_b   = (ushort_t*)(ws + off); off += 262144;
    ushort_t* Wms_b   = (ushort_t*)(ws + off); off += 1048576;
    float*    W2t     = (float*)(ws + off);    off += 131072;
    float*    bias0s  = (float*)(ws + off);    off += 4096;
    float*    bias1s  = (float*)(ws + off);    off += 4096;
    float*    bms     = (float*)(ws + off);    off += 4096;
    float*    accp    = (float*)(ws + off);    off += 256;
    char*     S       = ws + off;              // chunk scratch
    const size_t avail = (ws_size > off) ? (ws_size - off) : 0;

    // scan-phase chunk with buffer overlay:
    //   xgck: TC x 1 MB   (xg0, then xg1 reuses it — xg0 dead after scan0)
    //   fck : TC x 512 KB (feats, then h0s overlays — feats dead after xg0 GEMM)
    const size_t STEP_B = 1572864;
    int TC = (int)(avail / STEP_B);
    if (TC > 257) TC = 257;
    if (TC < 1)  TC = 1;
    // head-phase chunk: per row ph(1024)+pn(512)+msh(2048) = 3584 B; cap 24576 rows (~88 MB)
    long long rc = (long long)(avail / 3584) & ~127LL;
    if (rc > 24576) rc = 24576;
    if (rc < 128)   rc = 128;
    const int RC = (int)rc;

    hipMemsetAsync(accp, 0, 256, stream);

    PrepArgs pa{ Wfe, Wih0, Whh0, bih0, bhh0, Wih1, Whh1, bih1, bhh1,
                 Wf1, Wf2, Wm1, Ws1, Wm2, Ws2, bm1, bs1,
                 Wfe_b, Wih0_b, Wih1_b, wt0, wt1, Wf1_b, Wf2_b, Wms_b,
                 W2t, bias0s, bias1s, bms };
    prep_k<<<512, 256, 0, stream>>>(pa);

    // ---------- scan phase ----------
    ushort_t* xgck = (ushort_t*)S;
    ushort_t* fck  = (ushort_t*)(S + (size_t)TC * 1048576);
    for (int jc = 0; jc < 257; jc += TC) {
        const int nsteps = (257 - jc < TC) ? (257 - jc) : TC;
        // feats = relu(states_chunk @ Wfe^T + bfe)      [N=512, K=128]
        gemm_k<0, 1, float, float><<<nsteps * 16, 256, 0, stream>>>(
            states + (size_t)jc * 512 * 128, nullptr, Wfe_b, bfe, fck, 128, 512);
        // xg0 = feats @ Wih0^T + (bih0 + bhh0)          [N=1024, K=512]
        gemm_k<0, 0, ushort_t, ushort_t><<<nsteps * 32, 256, 0, stream>>>(
            fck, nullptr, Wih0_b, bias0s, xgck, 512, 1024);
        // layer-0 scan — h0s overlays feats region
        ScanArgs sa0{ xgck, dones, wt0, fck, h0st, c0st, jc, nsteps, (jc == 0) ? 1 : 0 };
        scan_r_k<<<256, 512, 0, stream>>>(sa0);
        // xg1 = h0s @ Wih1^T + (bih1 + bhh1)            [N=1024, K=256] — xg1 reuses xgck
        gemm_k<0, 0, ushort_t, ushort_t><<<nsteps * 32, 256, 0, stream>>>(
            fck, nullptr, Wih1_b, bias1s, xgck, 256, 1024);
        // layer-1 scan
        ScanArgs sa1{ xgck, dones, wt1, outs + (size_t)jc * 131072,
                      h1st, c1st, jc, nsteps, (jc == 0) ? 1 : 0 };
        scan_r_k<<<256, 512, 0, stream>>>(sa1);
    }

    // ---------- head phase (row-chunked, L3-resident chunks) ----------
    for (int r0 = 0; r0 < M_SEQ; r0 += RC) {
        const int rows = (M_SEQ - r0 < RC) ? (M_SEQ - r0) : RC;
        ushort_t* ph  = (ushort_t*)S;
        ushort_t* pn  = (ushort_t*)(S + (size_t)rows * 1024);
        ushort_t* msh = (ushort_t*)(S + (size_t)rows * 1536);
        // pred_hidden = relu([sf, action] @ Wf1^T + bf1)  [N=512, K=288]
        gemm_k<1, 1, ushort_t, float><<<(rows / 128) * 4, 256, 0, stream>>>(
            outs + (size_t)r0 * 256, action + (size_t)r0 * 32, Wf1_b, bf1, ph, 288, 512);
        // pred_next = pred_hidden @ Wf2^T + bf2           [N=256, K=512]
        gemm_k<0, 0, ushort_t, ushort_t><<<(rows / 128) * 2, 256, 0, stream>>>(
            ph, nullptr, Wf2_b, bf2, pn, 512, 256);
        // forward loss + intrinsic reward
        fl_k<<<rows / 4, 256, 0, stream>>>(pn, outs, (float*)d_out, accp, r0, out_size);
        // msh = relu([sf, pred_next] @ [Wm1;Ws1]^T + [bm1;bs1])  [N=1024, K=512]
        gemm_k<2, 1, ushort_t, ushort_t><<<(rows / 128) * 8, 256, 0, stream>>>(
            outs + (size_t)r0 * 256, pn, Wms_b, bms, msh, 512, 1024);
        // mu/std heads + inverse loss
        musd_k<<<rows / 8, 256, 0, stream>>>(msh, W2t, bm2, bs2, action, accp + 1, r0);
    }

    // scalars + hidden
    fin_k<<<2048, 256, 0, stream>>>(accp, h0st, h1st, c0st, c1st, (float*)d_out, out_size);
}

// Round 8
// 3410.038 us; speedup vs baseline: 1.4591x; 1.0009x over previous
//
#include <hip/hip_runtime.h>
#include <hip/hip_bf16.h>

typedef unsigned short ushort_t;
typedef unsigned int   uint_t;

// Problem constants: T1=257, B=512, SD=128, AD=32, HS=512, SF=256, L=2
#define M_ALL 131584   // 257*512
#define M_SEQ 131072   // 256*512

// ---------- helpers ----------
__device__ __forceinline__ float bf2f(ushort_t u) {
    union { uint_t i; float f; } v; v.i = ((uint_t)u) << 16; return v.f;
}
__device__ __forceinline__ ushort_t f2bf(float f) {
    union { float f; uint_t i; } v; v.f = f;
    uint_t r = v.i + 0x7FFFu + ((v.i >> 16) & 1u);
    return (ushort_t)(r >> 16);
}
__device__ __forceinline__ ushort_t f2h(float f) {
    union { _Float16 h; ushort_t u; } v; v.h = (_Float16)f; return v.u;
}
__device__ __forceinline__ float fsigm(float x) { return 1.f / (1.f + __expf(-x)); }
__device__ __forceinline__ float ftanh(float x) {
    x = fminf(15.f, fmaxf(-15.f, x));
    float e = __expf(2.f * x);
    return (e - 1.f) / (e + 1.f);
}

typedef __attribute__((ext_vector_type(8))) short  bfrag;   // 8 x bf16
typedef __attribute__((ext_vector_type(4))) float  ffrag;   // 4 x f32 accum
typedef __attribute__((ext_vector_type(2))) _Float16 h2v;   // 2 x f16

__device__ __forceinline__ h2v as_h2(uint_t x) {
    union { uint_t u; h2v h; } v; v.u = x; return v.h;
}
// f16 pair dot with f32 accumulate: v_dot2_f32_f16 (proven R2-R7)
__device__ __forceinline__ float dot2f(h2v a, h2v b, float acc) {
#if __has_builtin(__builtin_amdgcn_fdot2)
    return __builtin_amdgcn_fdot2(a, b, acc, false);
#else
    return acc + (float)a.x * (float)b.x + (float)a.y * (float)b.y;
#endif
}

// async global->LDS, 16B per lane; dest base must be wave-uniform (lane*16 auto)
typedef const __attribute__((address_space(1))) unsigned int as1_u32;
typedef __attribute__((address_space(3))) unsigned int as3_u32;
__device__ __forceinline__ void gload16(const void* g, void* l) {
    __builtin_amdgcn_global_load_lds((as1_u32*)g, (as3_u32*)l, 16, 0, 0);
}

// manual stage of 8 elements into LDS as bf16 (f32 source converts)
__device__ __forceinline__ void stage8(const float* p, ushort_t* dst) {
    const float4 a = *(const float4*)p;
    const float4 b = *(const float4*)(p + 4);
    bfrag v;
    v[0] = (short)f2bf(a.x); v[1] = (short)f2bf(a.y);
    v[2] = (short)f2bf(a.z); v[3] = (short)f2bf(a.w);
    v[4] = (short)f2bf(b.x); v[5] = (short)f2bf(b.y);
    v[6] = (short)f2bf(b.z); v[7] = (short)f2bf(b.w);
    *(bfrag*)dst = v;
}

// ---------- 256x128-tile bf16 MFMA GEMM, counted-vmcnt 2-phase pipeline ----------
// C = act(A @ W^T + bias), C bf16, W bf16, bias f32.
// R8: 512 threads / 8 waves (4M x 2N), 256x128 output tile. vs R7's 128x128:
// staging instr per output element -25% (3 gload16/thread vs 4), half the
// blocks (half prologue/epilogue/launch fixed cost), each W tile serves 2x
// the A rows. Same proven 2-phase counted-vmcnt K-loop. LDS 48 KB -> 3
// blocks/CU. Small-K fixed-cost amortization is the target (K = 128..512:
// only 4-16 K-iters; R7 showed refetch was NOT the bottleneck).
// AMODE 0: plain A1 (stride K)
// AMODE 1: k<256 -> A1 stride 256 ; k>=256 -> A2 stride 32  (x = [sf, action]), A2 f32
// AMODE 2: k<256 -> A1 stride 256 ; k>=256 -> A2 stride 256 (xi = [sf, pred_next])
template<int AMODE, int ACT, typename TA1, typename TA2>
__global__ __launch_bounds__(512) void gemm_k(
    const TA1* __restrict__ A1, const TA2* __restrict__ A2,
    const ushort_t* __restrict__ W, const float* __restrict__ b1,
    ushort_t* __restrict__ C, int K, int N)
{
    __shared__ __align__(16) ushort_t As[2][256][32];
    __shared__ __align__(16) ushort_t Ws[2][128][32];

    const int tid  = threadIdx.x;
    // XCD-chunked 1D swizzle, column fastest (identity if grid not /8)
    const int nwg  = (int)gridDim.x;
    const int p    = (int)blockIdx.x;
    const int l    = (nwg & 7) ? p : ((p & 7) * (nwg >> 3) + (p >> 3));
    const int ncol = N >> 7;                 // 2, 4 or 8 (power of 2)
    const int ncs  = 31 - __clz(ncol);
    const int m0   = (l >> ncs) * 256;
    const int n0   = (l & (ncol - 1)) * 128;
    const int lane = tid & 63;
    const int wv   = tid >> 6;               // 0..7
    const int wm   = (wv & 3) * 64;          // 4 M-slots
    const int wn   = (wv >> 2) * 64;         // 2 N-slots
    const int quad = lane >> 4;
    const int ln   = lane & 15;

    ffrag acc[4][4];
#pragma unroll
    for (int i = 0; i < 4; i++)
#pragma unroll
        for (int j = 0; j < 4; j++) acc[i][j] = (ffrag){0.f, 0.f, 0.f, 0.f};

    const int grow = lane >> 2;        // 0..15: row within a 16-row gload group
    const int gcol = (lane & 3) * 8;   // element col 0,8,16,24
    const int arow = tid >> 2;         // 0..127 manual-stage row (+128 via rr)
    const int acol = (tid & 3) * 8;

    auto stage = [&](int buf, int k0) {
        // W: 128 rows, one gload16 per wave
        gload16(W + (size_t)(n0 + (wv << 4) + grow) * K + k0 + gcol, &Ws[buf][wv << 4][0]);
        // A: 256 rows
        if constexpr (sizeof(TA1) == 4) {
#pragma unroll
            for (int rr = 0; rr < 2; rr++)
                stage8((const float*)A1 + (size_t)(m0 + arow + rr * 128) * K + k0 + acol,
                       &As[buf][arow + rr * 128][acol]);
        } else {
            if (AMODE == 1 && sizeof(TA2) == 4 && k0 >= 256) {
#pragma unroll
                for (int rr = 0; rr < 2; rr++)
                    stage8((const float*)A2 + (size_t)(m0 + arow + rr * 128) * 32 + (k0 - 256) + acol,
                           &As[buf][arow + rr * 128][acol]);
            } else {
#pragma unroll
                for (int c = 0; c < 2; c++) {
                    const int rb = (wv << 5) + (c << 4);
                    const int r  = rb + grow;
                    const ushort_t* src;
                    if (AMODE == 0)     src = (const ushort_t*)A1 + (size_t)(m0 + r) * K + k0 + gcol;
                    else if (k0 < 256)  src = (const ushort_t*)A1 + (size_t)(m0 + r) * 256 + k0 + gcol;
                    else                src = (const ushort_t*)A2 + (size_t)(m0 + r) * 256 + (k0 - 256) + gcol; // AMODE 2
                    gload16(src, &As[buf][rb][0]);
                }
            }
        }
    };
    auto compute = [&](int buf) {
        bfrag af[4], bfv[4];
#pragma unroll
        for (int i = 0; i < 4; i++) af[i]  = *(const bfrag*)&As[buf][wm + i * 16 + ln][quad * 8];
#pragma unroll
        for (int j = 0; j < 4; j++) bfv[j] = *(const bfrag*)&Ws[buf][wn + j * 16 + ln][quad * 8];
#pragma unroll
        for (int i = 0; i < 4; i++)
#pragma unroll
            for (int j = 0; j < 4; j++)
                acc[i][j] = __builtin_amdgcn_mfma_f32_16x16x32_bf16(af[i], bfv[j], acc[i][j], 0, 0, 0);
    };

    stage(0, 0);
    int cur = 0;
    for (int k0 = 32; k0 < K; k0 += 32) {
        stage(cur ^ 1, k0);   // issue next tile; stays in flight through compute
        // counted wait: drain PREVIOUS tile's staging only (this iter's stays in flight)
        if constexpr (sizeof(TA1) == 4) {
            asm volatile("s_waitcnt vmcnt(1) lgkmcnt(0)" ::: "memory");
        } else if constexpr (AMODE == 1 && sizeof(TA2) == 4) {
            if (k0 >= 256) asm volatile("s_waitcnt vmcnt(1) lgkmcnt(0)" ::: "memory");
            else           asm volatile("s_waitcnt vmcnt(3)" ::: "memory");
        } else {
            asm volatile("s_waitcnt vmcnt(3)" ::: "memory");
        }
        __builtin_amdgcn_sched_barrier(0);
        asm volatile("s_barrier" ::: "memory");
        compute(cur);
        asm volatile("s_waitcnt lgkmcnt(0)" ::: "memory");
        __builtin_amdgcn_sched_barrier(0);
        asm volatile("s_barrier" ::: "memory");
        cur ^= 1;
    }
    asm volatile("s_waitcnt vmcnt(0) lgkmcnt(0)" ::: "memory");
    __builtin_amdgcn_sched_barrier(0);
    asm volatile("s_barrier" ::: "memory");
    compute(cur);

#pragma unroll
    for (int j = 0; j < 4; j++) {
        const int n = n0 + wn + j * 16 + ln;
        const float bias = b1[n];
#pragma unroll
        for (int i = 0; i < 4; i++) {
#pragma unroll
            for (int r = 0; r < 4; r++) {
                const int m = m0 + wm + i * 16 + quad * 4 + r;
                float x = acc[i][j][r] + bias;
                if (ACT == 1) x = fmaxf(x, 0.f);
                C[(size_t)m * N + n] = f2bf(x);
            }
        }
    }
}

// ---------- prep ----------
// wt0/wt1: f16 pair-pack [k2][u][8] f16:
//   8 = {wi(2k2),wi(2k2+1), wf(2k2),wf(2k2+1), wg(2k2),wg(2k2+1), wo(2k2),wo(2k2+1)}
// -> uint4 per (k2,u) = 4 gate k-pairs, feeds v_dot2_f32_f16 directly.
struct PrepArgs {
    const float *Wfe, *Wih0, *Whh0, *bih0, *bhh0, *Wih1, *Whh1, *bih1, *bhh1;
    const float *Wf1, *Wf2, *Wm1, *Ws1, *Wm2, *Ws2;
    const float *bm1, *bs1;
    ushort_t *Wfe_b, *Wih0_b, *Wih1_b, *wt0, *wt1, *Wf1_b, *Wf2_b, *Wms_b;
    float *W2t, *bias0s, *bias1s, *bms;
};
__global__ __launch_bounds__(256) void prep_k(PrepArgs a)
{
    const int idx = blockIdx.x * 256 + threadIdx.x;
    const int stride = gridDim.x * 256;
    for (int e = idx; e < 65536; e += stride)  a.Wfe_b[e]  = f2bf(a.Wfe[e]);
    for (int e = idx; e < 524288; e += stride) a.Wih0_b[e] = f2bf(a.Wih0[e]);   // (1024,512)
    for (int e = idx; e < 262144; e += stride) a.Wih1_b[e] = f2bf(a.Wih1[e]);   // (1024,256)
    for (int e = idx; e < 262144; e += stride) {              // wt0: f16 pair-pack (Whh0)
        const int k2 = e >> 11, r = e & 2047;
        const int u = r >> 3, t = r & 7;
        const int g = t >> 1, wh = t & 1;
        const int kk = (k2 << 1) + wh;
        a.wt0[e] = f2h(a.Whh0[(g * 256 + u) * 256 + kk]);
    }
    for (int e = idx; e < 262144; e += stride) {              // wt1: f16 pair-pack (Whh1)
        const int k2 = e >> 11, r = e & 2047;
        const int u = r >> 3, t = r & 7;
        const int g = t >> 1, wh = t & 1;
        const int kk = (k2 << 1) + wh;
        a.wt1[e] = f2h(a.Whh1[(g * 256 + u) * 256 + kk]);
    }
    for (int e = idx; e < 147456; e += stride) a.Wf1_b[e] = f2bf(a.Wf1[e]);
    for (int e = idx; e < 131072; e += stride) a.Wf2_b[e] = f2bf(a.Wf2[e]);
    for (int e = idx; e < 524288; e += stride) {              // Wms_b: (1024,512) = [Wm1; Ws1]
        const int n = e >> 9, k = e & 511;
        a.Wms_b[e] = f2bf((n < 512) ? a.Wm1[n * 512 + k] : a.Ws1[(n - 512) * 512 + k]);
    }
    for (int e = idx; e < 32768; e += stride) {               // W2t: (512,64) k-major f32
        const int k = e >> 6, c = e & 63;
        a.W2t[e] = (c < 32) ? a.Wm2[c * 512 + k] : a.Ws2[(c - 32) * 512 + k];
    }
    for (int e = idx; e < 1024; e += stride) {
        a.bias0s[e] = a.bih0[e] + a.bhh0[e];
        a.bias1s[e] = a.bih1[e] + a.bhh1[e];
        a.bms[e]    = (e < 512) ? a.bm1[e] : a.bs1[e - 512];
    }
}

// ---------- persistent LSTM scan: hybrid VGPR+LDS weight residency (R6-proven) ----------
struct ScanArgs {
    const ushort_t* xg;      // (nsteps*512, 1024) bf16, gate order {i,f,g,o}x256
    const int*      dones;   // (257,512) int32, absolute t indexing
    const ushort_t* wt;      // f16 pair-packed recurrent weights [k2][u][8]
    ushort_t*       hout;    // bf16 h stream: (nsteps*512, 256), chunk-local s indexing
    float*          hst;     // persistent h (512*256 f32)
    float*          cst;     // persistent c (512*256 f32)
    int jc, nsteps, init;
};

#define DOTQ(W, H0, H1) do { \
    const h2v q0 = as_h2(H0), q1 = as_h2(H1); \
    p0i = dot2f(q0, as_h2((W).x), p0i); p0f = dot2f(q0, as_h2((W).y), p0f); \
    p0g = dot2f(q0, as_h2((W).z), p0g); p0o = dot2f(q0, as_h2((W).w), p0o); \
    p1i = dot2f(q1, as_h2((W).x), p1i); p1f = dot2f(q1, as_h2((W).y), p1f); \
    p1g = dot2f(q1, as_h2((W).z), p1g); p1o = dot2f(q1, as_h2((W).w), p1o); \
} while (0)

__global__ __launch_bounds__(512, 2) void scan_r_k(ScanArgs a)
{
    __shared__ __align__(16) ushort_t wlds[2][16][256][8];   // 128 KB weight parking
    __shared__ __align__(16) _Float16 xs[2][2][264];         // [phase][row][unit], padded
    const int tid = threadIdx.x;
    const int r = tid & 1, u = tid >> 1;
    const int b = blockIdx.x * 2 + r;
    float h = a.init ? 0.f : a.hst[b * 256 + u];
    float c = a.init ? 0.f : a.cst[b * 256 + u];

    // preload: 48 quads -> VGPRs, 16 quads -> LDS (both private to this thread)
    const ushort_t* wtu = a.wt + ((size_t)(r * 64) << 11) + 8 * u;
    uint4 wr[48];
#pragma unroll
    for (int j = 0; j < 48; ++j)
        wr[j] = *(const uint4*)(wtu + ((size_t)j << 11));
#pragma unroll
    for (int j = 0; j < 16; ++j)
        *(uint4*)&wlds[r][j][u][0] = *(const uint4*)(wtu + ((size_t)(48 + j) << 11));

    const int ks = r * 128;   // h-index base of this thread's k-half
    int ph = 0;
    float mval = 1.f - (float)a.dones[(size_t)a.jc * 512 + b];

    for (int sst = 0; sst < a.nsteps; ++sst) {
        xs[ph][r][u] = (_Float16)(h * mval);
        const float cold = c * mval;
        // prefetch next step's done mask (consumed next iteration)
        float mnext = 0.f;
        if (sst + 1 < a.nsteps)
            mnext = 1.f - (float)a.dones[(size_t)(a.jc + sst + 1) * 512 + b];
        // issue xg gate loads now; consumed after the dot loop
        const size_t base = ((size_t)sst * 512 + b) * 1024;
        const ushort_t g0 = a.xg[base + u];
        const ushort_t g1 = a.xg[base + 256 + u];
        const ushort_t g2 = a.xg[base + 512 + u];
        const ushort_t g3 = a.xg[base + 768 + u];
        __syncthreads();

        float p0i = 0.f, p0f = 0.f, p0g = 0.f, p0o = 0.f;   // row 0 partial (this k-half)
        float p1i = 0.f, p1f = 0.f, p1g = 0.f, p1o = 0.f;   // row 1 partial (this k-half)
        // quads 0..47 from VGPR
#pragma unroll
        for (int jj = 0; jj < 12; ++jj) {
            const uint4 h0 = *(const uint4*)&xs[ph][0][ks + jj * 8];
            const uint4 h1 = *(const uint4*)&xs[ph][1][ks + jj * 8];
            DOTQ(wr[jj * 4 + 0], h0.x, h1.x);
            DOTQ(wr[jj * 4 + 1], h0.y, h1.y);
            DOTQ(wr[jj * 4 + 2], h0.z, h1.z);
            DOTQ(wr[jj * 4 + 3], h0.w, h1.w);
        }
        // quads 48..63 from LDS parking
#pragma unroll
        for (int jj = 12; jj < 16; ++jj) {
            const uint4 h0 = *(const uint4*)&xs[ph][0][ks + jj * 8];
            const uint4 h1 = *(const uint4*)&xs[ph][1][ks + jj * 8];
            const uint4 w0 = *(const uint4*)&wlds[r][(jj - 12) * 4 + 0][u][0];
            const uint4 w1 = *(const uint4*)&wlds[r][(jj - 12) * 4 + 1][u][0];
            const uint4 w2 = *(const uint4*)&wlds[r][(jj - 12) * 4 + 2][u][0];
            const uint4 w3 = *(const uint4*)&wlds[r][(jj - 12) * 4 + 3][u][0];
            DOTQ(w0, h0.x, h1.x);
            DOTQ(w1, h0.y, h1.y);
            DOTQ(w2, h0.z, h1.z);
            DOTQ(w3, h0.w, h1.w);
        }

        // exchange other-half partials with partner lane (tid^1, same wave)
        const float s0 = (r == 0) ? p1i : p0i;
        const float s1 = (r == 0) ? p1f : p0f;
        const float s2 = (r == 0) ? p1g : p0g;
        const float s3 = (r == 0) ? p1o : p0o;
        const float o0 = __shfl_xor(s0, 1);
        const float o1 = __shfl_xor(s1, 1);
        const float o2 = __shfl_xor(s2, 1);
        const float o3 = __shfl_xor(s3, 1);

        const float ai  = ((r == 0) ? p0i : p1i) + o0 + bf2f(g0);
        const float af2 = ((r == 0) ? p0f : p1f) + o1 + bf2f(g1);
        const float ag  = ((r == 0) ? p0g : p1g) + o2 + bf2f(g2);
        const float ao  = ((r == 0) ? p0o : p1o) + o3 + bf2f(g3);

        const float c2 = fsigm(af2) * cold + fsigm(ai) * ftanh(ag);
        const float h2 = fsigm(ao) * ftanh(c2);
        c = c2; h = h2;
        a.hout[((size_t)sst * 512 + b) * 256 + u] = f2bf(h2);
        mval = mnext;
        ph ^= 1;
    }
    a.hst[b * 256 + u] = h;
    a.cst[b * 256 + u] = c;
}

// ---------- forward loss + intrinsic reward (row-chunked), f32 out ----------
__global__ __launch_bounds__(256) void fl_k(const ushort_t* __restrict__ pn,
                                            const ushort_t* __restrict__ outs,
                                            float* __restrict__ out, float* __restrict__ acc,
                                            int r0, int out_size)
{
    __shared__ float bs[4];
    const int tid = threadIdx.x;
    const int w = tid >> 6, l = tid & 63;
    const size_t rl = (size_t)blockIdx.x * 4 + w;
    const size_t rg = rl + r0;
    const ushort_t* p = pn + rl * 256;
    const ushort_t* q = outs + (rg + 512) * 256;   // next_state_features = outs[t+1]
    float s = 0.f;
#pragma unroll
    for (int i = 0; i < 4; i++) {
        const float d = bf2f(p[l + i * 64]) - bf2f(q[l + i * 64]);
        s += d * d;
    }
#pragma unroll
    for (int off = 32; off > 0; off >>= 1) s += __shfl_down(s, off);
    if (l == 0) { if ((long long)(2 + rg) < out_size) out[2 + rg] = s; bs[w] = s; }
    __syncthreads();
    if (tid == 0) atomicAdd(acc, bs[0] + bs[1] + bs[2] + bs[3]);
}

// ---------- fused mu/std heads + inverse loss (row-chunked), packed msh ----------
__global__ __launch_bounds__(256) void musd_k(
    const ushort_t* __restrict__ msh,    // (rows, 1024): [mh | sh]
    const float* __restrict__ W2t, const float* __restrict__ bm2,
    const float* __restrict__ bs2, const float* __restrict__ action,
    float* __restrict__ acc, int r0)
{
    __shared__ __align__(16) ushort_t mhs[8][512];
    __shared__ __align__(16) ushort_t shs[8][512];
    __shared__ float red[256];
    const int tid = threadIdx.x;
    const size_t rl0 = (size_t)blockIdx.x * 8;
    for (int i = tid; i < 512; i += 256) {
        const int row = i >> 6, c = (i & 63) * 8;
        *(uint4*)&mhs[row][c] = *(const uint4*)&msh[(rl0 + row) * 1024 + c];
        *(uint4*)&shs[row][c] = *(const uint4*)&msh[(rl0 + row) * 1024 + 512 + c];
    }
    __syncthreads();
    const int row = tid >> 5, c = tid & 31;
    float am = bm2[c], asv = bs2[c];
    for (int k = 0; k < 512; k += 8) {
#pragma unroll
        for (int e = 0; e < 8; e++) {
            const float wm = W2t[(k + e) * 64 + c];
            const float wsv = W2t[(k + e) * 64 + 32 + c];
            am  += bf2f(mhs[row][k + e]) * wm;
            asv += bf2f(shs[row][k + e]) * wsv;
        }
    }
    const float mu = ftanh(am);
    const float sp = fmaxf(asv, 0.f) + log1pf(__expf(-fabsf(asv)));   // softplus
    const float a  = action[(rl0 + r0 + row) * 32 + c];
    const float z  = (a - mu) / sp;
    red[tid] = 0.5f * z * z + __logf(sp) + 0.918938533204672741f;     // -log_prob
    __syncthreads();
    for (int s = 128; s > 0; s >>= 1) { if (tid < s) red[tid] += red[tid + s]; __syncthreads(); }
    if (tid == 0) atomicAdd(acc, red[0]);
}

// ---------- finalize: scalar losses + hidden copy-out (f32) ----------
__global__ __launch_bounds__(256) void fin_k(const float* __restrict__ acc,
                                             const float* __restrict__ h0st,
                                             const float* __restrict__ h1st,
                                             const float* __restrict__ c0st,
                                             const float* __restrict__ c1st,
                                             float* __restrict__ out, int out_size)
{
    const size_t idx = (size_t)blockIdx.x * 256 + threadIdx.x;
    if (idx == 0 && out_size > 0) out[0] = acc[0] / 33554432.f;   // mean over 256*512*256
    if (idx == 1 && out_size > 1) out[1] = acc[1] / 4194304.f;    // mean over 256*512*32
    if (idx < 524288) {
        const int which = (int)(idx >> 17);
        const int local = (int)(idx & 131071);
        float v;
        if      (which == 0) v = h0st[local];
        else if (which == 1) v = h1st[local];
        else if (which == 2) v = c0st[local];
        else                 v = c1st[local];
        const size_t o = 2 + 131072 + idx;
        if ((long long)o < out_size) out[o] = v;
    }
}

extern "C" void kernel_launch(void* const* d_in, const int* in_sizes, int n_in,
                              void* d_out, int out_size, void* d_ws, size_t ws_size,
                              hipStream_t stream)
{
    const float* states = (const float*)d_in[0];
    const float* action = (const float*)d_in[1];
    const int*   dones  = (const int*)d_in[2];
    const float* Wfe  = (const float*)d_in[3];
    const float* bfe  = (const float*)d_in[4];
    const float* Wih0 = (const float*)d_in[5];
    const float* Whh0 = (const float*)d_in[6];
    const float* bih0 = (const float*)d_in[7];
    const float* bhh0 = (const float*)d_in[8];
    const float* Wih1 = (const float*)d_in[9];
    const float* Whh1 = (const float*)d_in[10];
    const float* bih1 = (const float*)d_in[11];
    const float* bhh1 = (const float*)d_in[12];
    const float* Wf1  = (const float*)d_in[13];
    const float* bf1  = (const float*)d_in[14];
    const float* Wf2  = (const float*)d_in[15];
    const float* bf2  = (const float*)d_in[16];
    const float* Wm1  = (const float*)d_in[17];
    const float* bm1  = (const float*)d_in[18];
    const float* Wm2  = (const float*)d_in[19];
    const float* bm2  = (const float*)d_in[20];
    const float* Ws1  = (const float*)d_in[21];
    const float* bs1  = (const float*)d_in[22];
    const float* Ws2  = (const float*)d_in[23];
    const float* bs2  = (const float*)d_in[24];

    // ---------- workspace layout (persistent region) ----------
    char* ws = (char*)d_ws;
    size_t off = 0;
    ushort_t* outs    = (ushort_t*)(ws + off); off += 67371008;  // 257*512*256 bf16
    float*    h0st    = (float*)(ws + off);    off += 524288;
    float*    c0st    = (float*)(ws + off);    off += 524288;
    float*    h1st    = (float*)(ws + off);    off += 524288;
    float*    c1st    = (float*)(ws + off);    off += 524288;
    ushort_t* wt0     = (ushort_t*)(ws + off); off += 524288;    // f16 pairs [k2][u][8]
    ushort_t* wt1     = (ushort_t*)(ws + off); off += 524288;    // f16 pairs [k2][u][8]
    ushort_t* Wfe_b   = (ushort_t*)(ws + off); off += 131072;
    ushort_t* Wih0_b  = (ushort_t*)(ws + off); off += 1048576;
    ushort_t* Wih1_b  = (ushort_t*)(ws + off); off += 524288;
    ushort_t* Wf1_b   = (ushort_t*)(ws + off); off += 294912;
    ushort_t* Wf2_b   = (ushort_t*)(ws + off); off += 262144;
    ushort_t* Wms_b   = (ushort_t*)(ws + off); off += 1048576;
    float*    W2t     = (float*)(ws + off);    off += 131072;
    float*    bias0s  = (float*)(ws + off);    off += 4096;
    float*    bias1s  = (float*)(ws + off);    off += 4096;
    float*    bms     = (float*)(ws + off);    off += 4096;
    float*    accp    = (float*)(ws + off);    off += 256;
    char*     S       = ws + off;              // chunk scratch
    const size_t avail = (ws_size > off) ? (ws_size - off) : 0;

    // scan-phase chunk with buffer overlay:
    //   xgck: TC x 1 MB   (xg0, then xg1 reuses it — xg0 dead after scan0)
    //   fck : TC x 512 KB (feats, then h0s overlays — feats dead after xg0 GEMM)
    const size_t STEP_B = 1572864;
    int TC = (int)(avail / STEP_B);
    if (TC > 257) TC = 257;
    if (TC < 1)  TC = 1;
    // head-phase chunk: per row ph(1024)+pn(512)+msh(2048) = 3584 B; cap 24576 rows (~88 MB)
    // rows forced to multiple of 1024 so 256-row GEMM tiles divide evenly and
    // grids stay divisible by 8 for the XCD swizzle.
    long long rc = (long long)(avail / 3584) & ~1023LL;
    if (rc > 24576) rc = 24576;
    if (rc < 1024)  rc = 1024;
    const int RC = (int)rc;

    hipMemsetAsync(accp, 0, 256, stream);

    PrepArgs pa{ Wfe, Wih0, Whh0, bih0, bhh0, Wih1, Whh1, bih1, bhh1,
                 Wf1, Wf2, Wm1, Ws1, Wm2, Ws2, bm1, bs1,
                 Wfe_b, Wih0_b, Wih1_b, wt0, wt1, Wf1_b, Wf2_b, Wms_b,
                 W2t, bias0s, bias1s, bms };
    prep_k<<<512, 256, 0, stream>>>(pa);

    // ---------- scan phase ----------
    ushort_t* xgck = (ushort_t*)S;
    ushort_t* fck  = (ushort_t*)(S + (size_t)TC * 1048576);
    for (int jc = 0; jc < 257; jc += TC) {
        const int nsteps = (257 - jc < TC) ? (257 - jc) : TC;
        // feats = relu(states_chunk @ Wfe^T + bfe)      [N=512, K=128], M = nsteps*512
        gemm_k<0, 1, float, float><<<nsteps * 8, 512, 0, stream>>>(
            states + (size_t)jc * 512 * 128, nullptr, Wfe_b, bfe, fck, 128, 512);
        // xg0 = feats @ Wih0^T + (bih0 + bhh0)          [N=1024, K=512]
        gemm_k<0, 0, ushort_t, ushort_t><<<nsteps * 16, 512, 0, stream>>>(
            fck, nullptr, Wih0_b, bias0s, xgck, 512, 1024);
        // layer-0 scan — h0s overlays feats region
        ScanArgs sa0{ xgck, dones, wt0, fck, h0st, c0st, jc, nsteps, (jc == 0) ? 1 : 0 };
        scan_r_k<<<256, 512, 0, stream>>>(sa0);
        // xg1 = h0s @ Wih1^T + (bih1 + bhh1)            [N=1024, K=256] — xg1 reuses xgck
        gemm_k<0, 0, ushort_t, ushort_t><<<nsteps * 16, 512, 0, stream>>>(
            fck, nullptr, Wih1_b, bias1s, xgck, 256, 1024);
        // layer-1 scan
        ScanArgs sa1{ xgck, dones, wt1, outs + (size_t)jc * 131072,
                      h1st, c1st, jc, nsteps, (jc == 0) ? 1 : 0 };
        scan_r_k<<<256, 512, 0, stream>>>(sa1);
    }

    // ---------- head phase (row-chunked, L3-resident chunks) ----------
    for (int r0 = 0; r0 < M_SEQ; r0 += RC) {
        const int rows = (M_SEQ - r0 < RC) ? (M_SEQ - r0) : RC;
        const int tiles = rows / 256;
        ushort_t* ph  = (ushort_t*)S;
        ushort_t* pn  = (ushort_t*)(S + (size_t)rows * 1024);
        ushort_t* msh = (ushort_t*)(S + (size_t)rows * 1536);
        // pred_hidden = relu([sf, action] @ Wf1^T + bf1)  [N=512, K=288]
        gemm_k<1, 1, ushort_t, float><<<tiles * 4, 512, 0, stream>>>(
            outs + (size_t)r0 * 256, action + (size_t)r0 * 32, Wf1_b, bf1, ph, 288, 512);
        // pred_next = pred_hidden @ Wf2^T + bf2           [N=256, K=512]
        gemm_k<0, 0, ushort_t, ushort_t><<<tiles * 2, 512, 0, stream>>>(
            ph, nullptr, Wf2_b, bf2, pn, 512, 256);
        // forward loss + intrinsic reward
        fl_k<<<rows / 4, 256, 0, stream>>>(pn, outs, (float*)d_out, accp, r0, out_size);
        // msh = relu([sf, pred_next] @ [Wm1;Ws1]^T + [bm1;bs1])  [N=1024, K=512]
        gemm_k<2, 1, ushort_t, ushort_t><<<tiles * 8, 512, 0, stream>>>(
            outs + (size_t)r0 * 256, pn, Wms_b, bms, msh, 512, 1024);
        // mu/std heads + inverse loss
        musd_k<<<rows / 8, 256, 0, stream>>>(msh, W2t, bm2, bs2, action, accp + 1, r0);
    }

    // scalars + hidden
    fin_k<<<2048, 256, 0, stream>>>(accp, h0st, h1st, c0st, c1st, (float*)d_out, out_size);
}

// Round 9
// 2745.938 us; speedup vs baseline: 1.8119x; 1.2418x over previous
//
#include <hip/hip_runtime.h>
#include <hip/hip_bf16.h>

typedef unsigned short ushort_t;
typedef unsigned int   uint_t;

// Problem constants: T1=257, B=512, SD=128, AD=32, HS=512, SF=256, L=2
#define M_ALL 131584   // 257*512
#define M_SEQ 131072   // 256*512

// ---------- helpers ----------
__device__ __forceinline__ float bf2f(ushort_t u) {
    union { uint_t i; float f; } v; v.i = ((uint_t)u) << 16; return v.f;
}
__device__ __forceinline__ ushort_t f2bf(float f) {
    union { float f; uint_t i; } v; v.f = f;
    uint_t r = v.i + 0x7FFFu + ((v.i >> 16) & 1u);
    return (ushort_t)(r >> 16);
}
__device__ __forceinline__ ushort_t f2h(float f) {
    union { _Float16 h; ushort_t u; } v; v.h = (_Float16)f; return v.u;
}
__device__ __forceinline__ float fsigm(float x) { return 1.f / (1.f + __expf(-x)); }
__device__ __forceinline__ float ftanh(float x) {
    x = fminf(15.f, fmaxf(-15.f, x));
    float e = __expf(2.f * x);
    return (e - 1.f) / (e + 1.f);
}

typedef __attribute__((ext_vector_type(8))) short  bfrag;   // 8 x bf16
typedef __attribute__((ext_vector_type(4))) float  ffrag;   // 4 x f32 accum
typedef __attribute__((ext_vector_type(2))) _Float16 h2v;   // 2 x f16

__device__ __forceinline__ h2v as_h2(uint_t x) {
    union { uint_t u; h2v h; } v; v.u = x; return v.h;
}
// f16 pair dot with f32 accumulate: v_dot2_f32_f16 (proven R2-R8)
__device__ __forceinline__ float dot2f(h2v a, h2v b, float acc) {
#if __has_builtin(__builtin_amdgcn_fdot2)
    return __builtin_amdgcn_fdot2(a, b, acc, false);
#else
    return acc + (float)a.x * (float)b.x + (float)a.y * (float)b.y;
#endif
}

// async global->LDS, 16B per lane; dest base must be wave-uniform (lane*16 auto)
typedef const __attribute__((address_space(1))) unsigned int as1_u32;
typedef __attribute__((address_space(3))) unsigned int as3_u32;
__device__ __forceinline__ void gload16(const void* g, void* l) {
    __builtin_amdgcn_global_load_lds((as1_u32*)g, (as3_u32*)l, 16, 0, 0);
}

// manual stage of 8 elements into LDS as bf16 (f32 source converts)
__device__ __forceinline__ void stage8(const float* p, ushort_t* dst) {
    const float4 a = *(const float4*)p;
    const float4 b = *(const float4*)(p + 4);
    bfrag v;
    v[0] = (short)f2bf(a.x); v[1] = (short)f2bf(a.y);
    v[2] = (short)f2bf(a.z); v[3] = (short)f2bf(a.w);
    v[4] = (short)f2bf(b.x); v[5] = (short)f2bf(b.y);
    v[6] = (short)f2bf(b.z); v[7] = (short)f2bf(b.w);
    *(bfrag*)dst = v;
}

// ---------- 256x128-tile bf16 MFMA GEMM, counted-vmcnt 2-phase pipeline ----------
// C = act(A @ W^T + bias), W bf16, bias f32. OF32=0: C bf16; OF32=1: C f32.
// R8 structure (proven-neutral but stable): 512 threads / 8 waves (4M x 2N),
// 256x128 tile, XCD-chunked column-fastest 1D swizzle, counted-vmcnt 2-phase.
// AMODE 0: plain A1 (stride K)
// AMODE 1: k<256 -> A1 stride 256 ; k>=256 -> A2 stride 32  (x = [sf, action]), A2 f32
// AMODE 2: k<256 -> A1 stride 256 ; k>=256 -> A2 stride 256 (xi = [sf, pred_next])
template<int AMODE, int ACT, int OF32, typename TA1, typename TA2>
__global__ __launch_bounds__(512) void gemm_k(
    const TA1* __restrict__ A1, const TA2* __restrict__ A2,
    const ushort_t* __restrict__ W, const float* __restrict__ b1,
    ushort_t* __restrict__ C, int K, int N)
{
    __shared__ __align__(16) ushort_t As[2][256][32];
    __shared__ __align__(16) ushort_t Ws[2][128][32];

    const int tid  = threadIdx.x;
    // XCD-chunked 1D swizzle, column fastest (identity if grid not /8)
    const int nwg  = (int)gridDim.x;
    const int p    = (int)blockIdx.x;
    const int l    = (nwg & 7) ? p : ((p & 7) * (nwg >> 3) + (p >> 3));
    const int ncol = N >> 7;                 // 1, 2, 4 or 8 (power of 2)
    const int ncs  = 31 - __clz(ncol);
    const int m0   = (l >> ncs) * 256;
    const int n0   = (l & (ncol - 1)) * 128;
    const int lane = tid & 63;
    const int wv   = tid >> 6;               // 0..7
    const int wm   = (wv & 3) * 64;          // 4 M-slots
    const int wn   = (wv >> 2) * 64;         // 2 N-slots
    const int quad = lane >> 4;
    const int ln   = lane & 15;

    ffrag acc[4][4];
#pragma unroll
    for (int i = 0; i < 4; i++)
#pragma unroll
        for (int j = 0; j < 4; j++) acc[i][j] = (ffrag){0.f, 0.f, 0.f, 0.f};

    const int grow = lane >> 2;        // 0..15: row within a 16-row gload group
    const int gcol = (lane & 3) * 8;   // element col 0,8,16,24
    const int arow = tid >> 2;         // 0..127 manual-stage row (+128 via rr)
    const int acol = (tid & 3) * 8;

    auto stage = [&](int buf, int k0) {
        // W: 128 rows, one gload16 per wave
        gload16(W + (size_t)(n0 + (wv << 4) + grow) * K + k0 + gcol, &Ws[buf][wv << 4][0]);
        // A: 256 rows
        if constexpr (sizeof(TA1) == 4) {
#pragma unroll
            for (int rr = 0; rr < 2; rr++)
                stage8((const float*)A1 + (size_t)(m0 + arow + rr * 128) * K + k0 + acol,
                       &As[buf][arow + rr * 128][acol]);
        } else {
            if (AMODE == 1 && sizeof(TA2) == 4 && k0 >= 256) {
#pragma unroll
                for (int rr = 0; rr < 2; rr++)
                    stage8((const float*)A2 + (size_t)(m0 + arow + rr * 128) * 32 + (k0 - 256) + acol,
                           &As[buf][arow + rr * 128][acol]);
            } else {
#pragma unroll
                for (int c = 0; c < 2; c++) {
                    const int rb = (wv << 5) + (c << 4);
                    const int r  = rb + grow;
                    const ushort_t* src;
                    if (AMODE == 0)     src = (const ushort_t*)A1 + (size_t)(m0 + r) * K + k0 + gcol;
                    else if (k0 < 256)  src = (const ushort_t*)A1 + (size_t)(m0 + r) * 256 + k0 + gcol;
                    else                src = (const ushort_t*)A2 + (size_t)(m0 + r) * 256 + (k0 - 256) + gcol; // AMODE 2
                    gload16(src, &As[buf][rb][0]);
                }
            }
        }
    };
    auto compute = [&](int buf) {
        bfrag af[4], bfv[4];
#pragma unroll
        for (int i = 0; i < 4; i++) af[i]  = *(const bfrag*)&As[buf][wm + i * 16 + ln][quad * 8];
#pragma unroll
        for (int j = 0; j < 4; j++) bfv[j] = *(const bfrag*)&Ws[buf][wn + j * 16 + ln][quad * 8];
#pragma unroll
        for (int i = 0; i < 4; i++)
#pragma unroll
            for (int j = 0; j < 4; j++)
                acc[i][j] = __builtin_amdgcn_mfma_f32_16x16x32_bf16(af[i], bfv[j], acc[i][j], 0, 0, 0);
    };

    stage(0, 0);
    int cur = 0;
    for (int k0 = 32; k0 < K; k0 += 32) {
        stage(cur ^ 1, k0);   // issue next tile; stays in flight through compute
        // counted wait: drain PREVIOUS tile's staging only (this iter's stays in flight)
        if constexpr (sizeof(TA1) == 4) {
            asm volatile("s_waitcnt vmcnt(1) lgkmcnt(0)" ::: "memory");
        } else if constexpr (AMODE == 1 && sizeof(TA2) == 4) {
            if (k0 >= 256) asm volatile("s_waitcnt vmcnt(1) lgkmcnt(0)" ::: "memory");
            else           asm volatile("s_waitcnt vmcnt(3)" ::: "memory");
        } else {
            asm volatile("s_waitcnt vmcnt(3)" ::: "memory");
        }
        __builtin_amdgcn_sched_barrier(0);
        asm volatile("s_barrier" ::: "memory");
        compute(cur);
        asm volatile("s_waitcnt lgkmcnt(0)" ::: "memory");
        __builtin_amdgcn_sched_barrier(0);
        asm volatile("s_barrier" ::: "memory");
        cur ^= 1;
    }
    asm volatile("s_waitcnt vmcnt(0) lgkmcnt(0)" ::: "memory");
    __builtin_amdgcn_sched_barrier(0);
    asm volatile("s_barrier" ::: "memory");
    compute(cur);

#pragma unroll
    for (int j = 0; j < 4; j++) {
        const int n = n0 + wn + j * 16 + ln;
        const float bias = b1[n];
#pragma unroll
        for (int i = 0; i < 4; i++) {
#pragma unroll
            for (int r = 0; r < 4; r++) {
                const int m = m0 + wm + i * 16 + quad * 4 + r;
                float x = acc[i][j][r] + bias;
                if (ACT == 1) x = fmaxf(x, 0.f);
                if constexpr (OF32) ((float*)C)[(size_t)m * N + n] = x;
                else                C[(size_t)m * N + n] = f2bf(x);
            }
        }
    }
}

// ---------- prep ----------
// wt0/wt1: f16 pair-pack [k2][u][8]; W2b: (128,1024) bf16 zero-padded head-2
// weights rows 0-31=[Wm2|0], 32-63=[0|Ws2], 64-127=0; bmsv=[bm2|bs2|0] f32.
struct PrepArgs {
    const float *Wfe, *Wih0, *Whh0, *bih0, *bhh0, *Wih1, *Whh1, *bih1, *bhh1;
    const float *Wf1, *Wf2, *Wm1, *Ws1, *Wm2, *Ws2;
    const float *bm1, *bs1, *bm2, *bs2;
    ushort_t *Wfe_b, *Wih0_b, *Wih1_b, *wt0, *wt1, *Wf1_b, *Wf2_b, *Wms_b, *W2b;
    float *bmsv, *bias0s, *bias1s, *bms;
};
__global__ __launch_bounds__(256) void prep_k(PrepArgs a)
{
    const int idx = blockIdx.x * 256 + threadIdx.x;
    const int stride = gridDim.x * 256;
    for (int e = idx; e < 65536; e += stride)  a.Wfe_b[e]  = f2bf(a.Wfe[e]);
    for (int e = idx; e < 524288; e += stride) a.Wih0_b[e] = f2bf(a.Wih0[e]);   // (1024,512)
    for (int e = idx; e < 262144; e += stride) a.Wih1_b[e] = f2bf(a.Wih1[e]);   // (1024,256)
    for (int e = idx; e < 262144; e += stride) {              // wt0: f16 pair-pack (Whh0)
        const int k2 = e >> 11, r = e & 2047;
        const int u = r >> 3, t = r & 7;
        const int g = t >> 1, wh = t & 1;
        const int kk = (k2 << 1) + wh;
        a.wt0[e] = f2h(a.Whh0[(g * 256 + u) * 256 + kk]);
    }
    for (int e = idx; e < 262144; e += stride) {              // wt1: f16 pair-pack (Whh1)
        const int k2 = e >> 11, r = e & 2047;
        const int u = r >> 3, t = r & 7;
        const int g = t >> 1, wh = t & 1;
        const int kk = (k2 << 1) + wh;
        a.wt1[e] = f2h(a.Whh1[(g * 256 + u) * 256 + kk]);
    }
    for (int e = idx; e < 147456; e += stride) a.Wf1_b[e] = f2bf(a.Wf1[e]);
    for (int e = idx; e < 131072; e += stride) a.Wf2_b[e] = f2bf(a.Wf2[e]);
    for (int e = idx; e < 524288; e += stride) {              // Wms_b: (1024,512) = [Wm1; Ws1]
        const int n = e >> 9, k = e & 511;
        a.Wms_b[e] = f2bf((n < 512) ? a.Wm1[n * 512 + k] : a.Ws1[(n - 512) * 512 + k]);
    }
    for (int e = idx; e < 131072; e += stride) {              // W2b: (128,1024) zero-padded
        const int n = e >> 10, k = e & 1023;
        float v = 0.f;
        if (n < 32)       { if (k < 512)  v = a.Wm2[n * 512 + k]; }
        else if (n < 64)  { if (k >= 512) v = a.Ws2[(n - 32) * 512 + (k - 512)]; }
        a.W2b[e] = f2bf(v);
    }
    for (int e = idx; e < 1024; e += stride) {
        a.bias0s[e] = a.bih0[e] + a.bhh0[e];
        a.bias1s[e] = a.bih1[e] + a.bhh1[e];
        a.bms[e]    = (e < 512) ? a.bm1[e] : a.bs1[e - 512];
        if (e < 128) a.bmsv[e] = (e < 32) ? a.bm2[e] : ((e < 64) ? a.bs2[e - 32] : 0.f);
    }
}

// ---------- persistent LSTM scan: hybrid VGPR+LDS weight residency (R6-proven) ----------
struct ScanArgs {
    const ushort_t* xg;      // (nsteps*512, 1024) bf16, gate order {i,f,g,o}x256
    const int*      dones;   // (257,512) int32, absolute t indexing
    const ushort_t* wt;      // f16 pair-packed recurrent weights [k2][u][8]
    ushort_t*       hout;    // bf16 h stream: (nsteps*512, 256), chunk-local s indexing
    float*          hst;     // persistent h (512*256 f32)
    float*          cst;     // persistent c (512*256 f32)
    int jc, nsteps, init;
};

#define DOTQ(W, H0, H1) do { \
    const h2v q0 = as_h2(H0), q1 = as_h2(H1); \
    p0i = dot2f(q0, as_h2((W).x), p0i); p0f = dot2f(q0, as_h2((W).y), p0f); \
    p0g = dot2f(q0, as_h2((W).z), p0g); p0o = dot2f(q0, as_h2((W).w), p0o); \
    p1i = dot2f(q1, as_h2((W).x), p1i); p1f = dot2f(q1, as_h2((W).y), p1f); \
    p1g = dot2f(q1, as_h2((W).z), p1g); p1o = dot2f(q1, as_h2((W).w), p1o); \
} while (0)

__global__ __launch_bounds__(512, 2) void scan_r_k(ScanArgs a)
{
    __shared__ __align__(16) ushort_t wlds[2][16][256][8];   // 128 KB weight parking
    __shared__ __align__(16) _Float16 xs[2][2][264];         // [phase][row][unit], padded
    const int tid = threadIdx.x;
    const int r = tid & 1, u = tid >> 1;
    const int b = blockIdx.x * 2 + r;
    float h = a.init ? 0.f : a.hst[b * 256 + u];
    float c = a.init ? 0.f : a.cst[b * 256 + u];

    // preload: 48 quads -> VGPRs, 16 quads -> LDS (both private to this thread)
    const ushort_t* wtu = a.wt + ((size_t)(r * 64) << 11) + 8 * u;
    uint4 wr[48];
#pragma unroll
    for (int j = 0; j < 48; ++j)
        wr[j] = *(const uint4*)(wtu + ((size_t)j << 11));
#pragma unroll
    for (int j = 0; j < 16; ++j)
        *(uint4*)&wlds[r][j][u][0] = *(const uint4*)(wtu + ((size_t)(48 + j) << 11));

    const int ks = r * 128;   // h-index base of this thread's k-half
    int ph = 0;
    float mval = 1.f - (float)a.dones[(size_t)a.jc * 512 + b];

    for (int sst = 0; sst < a.nsteps; ++sst) {
        xs[ph][r][u] = (_Float16)(h * mval);
        const float cold = c * mval;
        // prefetch next step's done mask (consumed next iteration)
        float mnext = 0.f;
        if (sst + 1 < a.nsteps)
            mnext = 1.f - (float)a.dones[(size_t)(a.jc + sst + 1) * 512 + b];
        // issue xg gate loads now; consumed after the dot loop
        const size_t base = ((size_t)sst * 512 + b) * 1024;
        const ushort_t g0 = a.xg[base + u];
        const ushort_t g1 = a.xg[base + 256 + u];
        const ushort_t g2 = a.xg[base + 512 + u];
        const ushort_t g3 = a.xg[base + 768 + u];
        __syncthreads();

        float p0i = 0.f, p0f = 0.f, p0g = 0.f, p0o = 0.f;   // row 0 partial (this k-half)
        float p1i = 0.f, p1f = 0.f, p1g = 0.f, p1o = 0.f;   // row 1 partial (this k-half)
        // quads 0..47 from VGPR
#pragma unroll
        for (int jj = 0; jj < 12; ++jj) {
            const uint4 h0 = *(const uint4*)&xs[ph][0][ks + jj * 8];
            const uint4 h1 = *(const uint4*)&xs[ph][1][ks + jj * 8];
            DOTQ(wr[jj * 4 + 0], h0.x, h1.x);
            DOTQ(wr[jj * 4 + 1], h0.y, h1.y);
            DOTQ(wr[jj * 4 + 2], h0.z, h1.z);
            DOTQ(wr[jj * 4 + 3], h0.w, h1.w);
        }
        // quads 48..63 from LDS parking
#pragma unroll
        for (int jj = 12; jj < 16; ++jj) {
            const uint4 h0 = *(const uint4*)&xs[ph][0][ks + jj * 8];
            const uint4 h1 = *(const uint4*)&xs[ph][1][ks + jj * 8];
            const uint4 w0 = *(const uint4*)&wlds[r][(jj - 12) * 4 + 0][u][0];
            const uint4 w1 = *(const uint4*)&wlds[r][(jj - 12) * 4 + 1][u][0];
            const uint4 w2 = *(const uint4*)&wlds[r][(jj - 12) * 4 + 2][u][0];
            const uint4 w3 = *(const uint4*)&wlds[r][(jj - 12) * 4 + 3][u][0];
            DOTQ(w0, h0.x, h1.x);
            DOTQ(w1, h0.y, h1.y);
            DOTQ(w2, h0.z, h1.z);
            DOTQ(w3, h0.w, h1.w);
        }

        // exchange other-half partials with partner lane (tid^1, same wave)
        const float s0 = (r == 0) ? p1i : p0i;
        const float s1 = (r == 0) ? p1f : p0f;
        const float s2 = (r == 0) ? p1g : p0g;
        const float s3 = (r == 0) ? p1o : p0o;
        const float o0 = __shfl_xor(s0, 1);
        const float o1 = __shfl_xor(s1, 1);
        const float o2 = __shfl_xor(s2, 1);
        const float o3 = __shfl_xor(s3, 1);

        const float ai  = ((r == 0) ? p0i : p1i) + o0 + bf2f(g0);
        const float af2 = ((r == 0) ? p0f : p1f) + o1 + bf2f(g1);
        const float ag  = ((r == 0) ? p0g : p1g) + o2 + bf2f(g2);
        const float ao  = ((r == 0) ? p0o : p1o) + o3 + bf2f(g3);

        const float c2 = fsigm(af2) * cold + fsigm(ai) * ftanh(ag);
        const float h2 = fsigm(ao) * ftanh(c2);
        c = c2; h = h2;
        a.hout[((size_t)sst * 512 + b) * 256 + u] = f2bf(h2);
        mval = mnext;
        ph ^= 1;
    }
    a.hst[b * 256 + u] = h;
    a.cst[b * 256 + u] = c;
}

// ---------- forward loss + intrinsic reward: 32 rows/block (8 per wave) ----------
__global__ __launch_bounds__(256) void fl_k(const ushort_t* __restrict__ pn,
                                            const ushort_t* __restrict__ outs,
                                            float* __restrict__ out, float* __restrict__ acc,
                                            int r0, int out_size)
{
    __shared__ float bs[4];
    const int tid = threadIdx.x;
    const int w = tid >> 6, l = tid & 63;
    const size_t rb0 = (size_t)blockIdx.x * 32 + w * 8;
    float tot = 0.f;
#pragma unroll
    for (int it = 0; it < 8; ++it) {
        const size_t rl = rb0 + it;
        const size_t rg = rl + r0;
        const ushort_t* p = pn + rl * 256;
        const ushort_t* q = outs + (rg + 512) * 256;   // next_state_features = outs[t+1]
        float s = 0.f;
#pragma unroll
        for (int i = 0; i < 4; i++) {
            const float d = bf2f(p[l + i * 64]) - bf2f(q[l + i * 64]);
            s += d * d;
        }
#pragma unroll
        for (int off = 32; off > 0; off >>= 1) s += __shfl_down(s, off);
        if (l == 0) { if ((long long)(2 + rg) < out_size) out[2 + rg] = s; tot += s; }
    }
    if (l == 0) bs[w] = tot;
    __syncthreads();
    if (tid == 0) atomicAdd(acc, bs[0] + bs[1] + bs[2] + bs[3]);
}

// ---------- mu/std finish: elementwise on msv (GEMM did the contractions) ----------
// msv row: [am(32) | asv(32) | pad(64)] f32, bias already applied by GEMM.
__global__ __launch_bounds__(256) void musd2_k(
    const float* __restrict__ msv, const float* __restrict__ action,
    float* __restrict__ acc, int r0)
{
    __shared__ float red[256];
    const int tid = threadIdx.x;
    const int c = tid & 31, rr = tid >> 5;          // 8 row-groups
    const size_t rl0 = (size_t)blockIdx.x * 64;
    float s = 0.f;
#pragma unroll
    for (int it = 0; it < 8; ++it) {
        const size_t row = rl0 + rr * 8 + it;
        const float am  = msv[row * 128 + c];
        const float asv = msv[row * 128 + 32 + c];
        const float mu  = ftanh(am);
        const float sp  = fmaxf(asv, 0.f) + log1pf(__expf(-fabsf(asv)));   // softplus
        const float a   = action[(row + r0) * 32 + c];
        const float z   = (a - mu) / sp;
        s += 0.5f * z * z + __logf(sp) + 0.918938533204672741f;            // -log_prob
    }
    red[tid] = s;
    __syncthreads();
    for (int st = 128; st > 0; st >>= 1) { if (tid < st) red[tid] += red[tid + st]; __syncthreads(); }
    if (tid == 0) atomicAdd(acc, red[0]);
}

// ---------- finalize: scalar losses + hidden copy-out (f32) ----------
__global__ __launch_bounds__(256) void fin_k(const float* __restrict__ acc,
                                             const float* __restrict__ h0st,
                                             const float* __restrict__ h1st,
                                             const float* __restrict__ c0st,
                                             const float* __restrict__ c1st,
                                             float* __restrict__ out, int out_size)
{
    const size_t idx = (size_t)blockIdx.x * 256 + threadIdx.x;
    if (idx == 0 && out_size > 0) out[0] = acc[0] / 33554432.f;   // mean over 256*512*256
    if (idx == 1 && out_size > 1) out[1] = acc[1] / 4194304.f;    // mean over 256*512*32
    if (idx < 524288) {
        const int which = (int)(idx >> 17);
        const int local = (int)(idx & 131071);
        float v;
        if      (which == 0) v = h0st[local];
        else if (which == 1) v = h1st[local];
        else if (which == 2) v = c0st[local];
        else                 v = c1st[local];
        const size_t o = 2 + 131072 + idx;
        if ((long long)o < out_size) out[o] = v;
    }
}

extern "C" void kernel_launch(void* const* d_in, const int* in_sizes, int n_in,
                              void* d_out, int out_size, void* d_ws, size_t ws_size,
                              hipStream_t stream)
{
    const float* states = (const float*)d_in[0];
    const float* action = (const float*)d_in[1];
    const int*   dones  = (const int*)d_in[2];
    const float* Wfe  = (const float*)d_in[3];
    const float* bfe  = (const float*)d_in[4];
    const float* Wih0 = (const float*)d_in[5];
    const float* Whh0 = (const float*)d_in[6];
    const float* bih0 = (const float*)d_in[7];
    const float* bhh0 = (const float*)d_in[8];
    const float* Wih1 = (const float*)d_in[9];
    const float* Whh1 = (const float*)d_in[10];
    const float* bih1 = (const float*)d_in[11];
    const float* bhh1 = (const float*)d_in[12];
    const float* Wf1  = (const float*)d_in[13];
    const float* bf1  = (const float*)d_in[14];
    const float* Wf2  = (const float*)d_in[15];
    const float* bf2  = (const float*)d_in[16];
    const float* Wm1  = (const float*)d_in[17];
    const float* bm1  = (const float*)d_in[18];
    const float* Wm2  = (const float*)d_in[19];
    const float* bm2  = (const float*)d_in[20];
    const float* Ws1  = (const float*)d_in[21];
    const float* bs1  = (const float*)d_in[22];
    const float* Ws2  = (const float*)d_in[23];
    const float* bs2  = (const float*)d_in[24];

    // ---------- workspace layout (persistent region) ----------
    char* ws = (char*)d_ws;
    size_t off = 0;
    ushort_t* outs    = (ushort_t*)(ws + off); off += 67371008;  // 257*512*256 bf16
    float*    h0st    = (float*)(ws + off);    off += 524288;
    float*    c0st    = (float*)(ws + off);    off += 524288;
    float*    h1st    = (float*)(ws + off);    off += 524288;
    float*    c1st    = (float*)(ws + off);    off += 524288;
    ushort_t* wt0     = (ushort_t*)(ws + off); off += 524288;    // f16 pairs [k2][u][8]
    ushort_t* wt1     = (ushort_t*)(ws + off); off += 524288;    // f16 pairs [k2][u][8]
    ushort_t* Wfe_b   = (ushort_t*)(ws + off); off += 131072;
    ushort_t* Wih0_b  = (ushort_t*)(ws + off); off += 1048576;
    ushort_t* Wih1_b  = (ushort_t*)(ws + off); off += 524288;
    ushort_t* Wf1_b   = (ushort_t*)(ws + off); off += 294912;
    ushort_t* Wf2_b   = (ushort_t*)(ws + off); off += 262144;
    ushort_t* Wms_b   = (ushort_t*)(ws + off); off += 1048576;
    ushort_t* W2b     = (ushort_t*)(ws + off); off += 262144;    // (128,1024) bf16 padded
    float*    bmsv    = (float*)(ws + off);    off += 4096;
    float*    bias0s  = (float*)(ws + off);    off += 4096;
    float*    bias1s  = (float*)(ws + off);    off += 4096;
    float*    bms     = (float*)(ws + off);    off += 4096;
    float*    accp    = (float*)(ws + off);    off += 256;
    char*     S       = ws + off;              // chunk scratch
    const size_t avail = (ws_size > off) ? (ws_size - off) : 0;

    // scan-phase chunk with buffer overlay:
    //   xgck: TC x 1 MB   (xg0, then xg1 reuses it — xg0 dead after scan0)
    //   fck : TC x 512 KB (feats, then h0s overlays — feats dead after xg0 GEMM)
    const size_t STEP_B = 1572864;
    int TC = (int)(avail / STEP_B);
    if (TC > 257) TC = 257;
    if (TC < 1)  TC = 1;
    // head-phase chunk: per row ph(1024)+pn(512)+msh(2048)+msv(512) = 4096 B;
    // cap 24576 rows (~100 MB, L3-resident). Multiple of 1024 so 256-row GEMM
    // tiles divide and grids stay divisible by 8 for the XCD swizzle.
    long long rc = (long long)(avail / 4096) & ~1023LL;
    if (rc > 24576) rc = 24576;
    if (rc < 1024)  rc = 1024;
    const int RC = (int)rc;

    hipMemsetAsync(accp, 0, 256, stream);

    PrepArgs pa{ Wfe, Wih0, Whh0, bih0, bhh0, Wih1, Whh1, bih1, bhh1,
                 Wf1, Wf2, Wm1, Ws1, Wm2, Ws2, bm1, bs1, bm2, bs2,
                 Wfe_b, Wih0_b, Wih1_b, wt0, wt1, Wf1_b, Wf2_b, Wms_b, W2b,
                 bmsv, bias0s, bias1s, bms };
    prep_k<<<512, 256, 0, stream>>>(pa);

    // ---------- scan phase ----------
    ushort_t* xgck = (ushort_t*)S;
    ushort_t* fck  = (ushort_t*)(S + (size_t)TC * 1048576);
    for (int jc = 0; jc < 257; jc += TC) {
        const int nsteps = (257 - jc < TC) ? (257 - jc) : TC;
        // feats = relu(states_chunk @ Wfe^T + bfe)      [N=512, K=128], M = nsteps*512
        gemm_k<0, 1, 0, float, float><<<nsteps * 8, 512, 0, stream>>>(
            states + (size_t)jc * 512 * 128, nullptr, Wfe_b, bfe, fck, 128, 512);
        // xg0 = feats @ Wih0^T + (bih0 + bhh0)          [N=1024, K=512]
        gemm_k<0, 0, 0, ushort_t, ushort_t><<<nsteps * 16, 512, 0, stream>>>(
            fck, nullptr, Wih0_b, bias0s, xgck, 512, 1024);
        // layer-0 scan — h0s overlays feats region
        ScanArgs sa0{ xgck, dones, wt0, fck, h0st, c0st, jc, nsteps, (jc == 0) ? 1 : 0 };
        scan_r_k<<<256, 512, 0, stream>>>(sa0);
        // xg1 = h0s @ Wih1^T + (bih1 + bhh1)            [N=1024, K=256] — xg1 reuses xgck
        gemm_k<0, 0, 0, ushort_t, ushort_t><<<nsteps * 16, 512, 0, stream>>>(
            fck, nullptr, Wih1_b, bias1s, xgck, 256, 1024);
        // layer-1 scan
        ScanArgs sa1{ xgck, dones, wt1, outs + (size_t)jc * 131072,
                      h1st, c1st, jc, nsteps, (jc == 0) ? 1 : 0 };
        scan_r_k<<<256, 512, 0, stream>>>(sa1);
    }

    // ---------- head phase (row-chunked, L3-resident chunks) ----------
    for (int r0 = 0; r0 < M_SEQ; r0 += RC) {
        const int rows = (M_SEQ - r0 < RC) ? (M_SEQ - r0) : RC;
        const int tiles = rows / 256;
        ushort_t* ph  = (ushort_t*)S;
        ushort_t* pn  = (ushort_t*)(S + (size_t)rows * 1024);
        ushort_t* msh = (ushort_t*)(S + (size_t)rows * 1536);
        float*    msv = (float*)(S + (size_t)rows * 3584);
        // pred_hidden = relu([sf, action] @ Wf1^T + bf1)  [N=512, K=288]
        gemm_k<1, 1, 0, ushort_t, float><<<tiles * 4, 512, 0, stream>>>(
            outs + (size_t)r0 * 256, action + (size_t)r0 * 32, Wf1_b, bf1, ph, 288, 512);
        // pred_next = pred_hidden @ Wf2^T + bf2           [N=256, K=512]
        gemm_k<0, 0, 0, ushort_t, ushort_t><<<tiles * 2, 512, 0, stream>>>(
            ph, nullptr, Wf2_b, bf2, pn, 512, 256);
        // forward loss + intrinsic reward
        fl_k<<<rows / 32, 256, 0, stream>>>(pn, outs, (float*)d_out, accp, r0, out_size);
        // msh = relu([sf, pred_next] @ [Wm1;Ws1]^T + [bm1;bs1])  [N=1024, K=512]
        gemm_k<2, 1, 0, ushort_t, ushort_t><<<tiles * 8, 512, 0, stream>>>(
            outs + (size_t)r0 * 256, pn, Wms_b, bms, msh, 512, 1024);
        // msv = msh @ W2b^T + bmsv   [N=128, K=1024, f32 out] — mu/std contractions on MFMA
        gemm_k<0, 0, 1, ushort_t, ushort_t><<<tiles, 512, 0, stream>>>(
            msh, nullptr, W2b, bmsv, (ushort_t*)msv, 1024, 128);
        // mu/std finish + inverse loss
        musd2_k<<<rows / 64, 256, 0, stream>>>(msv, action + (size_t)r0 * 32 - (size_t)r0 * 32,
                                               accp + 1, r0);
    }

    // scalars + hidden
    fin_k<<<2048, 256, 0, stream>>>(accp, h0st, h1st, c0st, c1st, (float*)d_out, out_size);
}